// Round 10
// baseline (823.679 us; speedup 1.0000x reference)
//
#include <hip/hip_runtime.h>
#include <hip/hip_fp16.h>

typedef unsigned short ushortT;
typedef _Float16 f16x8 __attribute__((ext_vector_type(8)));
typedef __attribute__((ext_vector_type(4))) float float4v;
typedef __attribute__((ext_vector_type(4))) unsigned int uint4v;

__device__ __forceinline__ unsigned short f2h(float f) {  // RTNE f32->f16 (v_cvt_f16_f32)
    _Float16 h = (_Float16)f;
    return __builtin_bit_cast(unsigned short, h);
}
__device__ __forceinline__ float h2f(unsigned short b) {  // v_cvt_f32_f16
    return (float)__builtin_bit_cast(_Float16, b);
}
// packed f32x2 -> f16x2, RTZ (v_cvt_pkrtz_f16_f32, 1 inst).
__device__ __forceinline__ unsigned pkrtz(float lo, float hi) {
    auto h = __builtin_amdgcn_cvt_pkrtz(lo, hi);
    return __builtin_bit_cast(unsigned, h);
}
__device__ __forceinline__ void unpack8(uint4 v, float o[8]) {
    unsigned uu[4] = {v.x, v.y, v.z, v.w};
    #pragma unroll
    for (int j = 0; j < 8; j++) o[j] = h2f((unsigned short)(uu[j >> 1] >> ((j & 1) * 16)));
}
__device__ __forceinline__ void unpack_add(uint4 v, float a[8]) {  // f16 pairs
    unsigned uu[4] = {v.x, v.y, v.z, v.w};
    #pragma unroll
    for (int j = 0; j < 8; j++) a[j] += h2f((unsigned short)(uu[j >> 1] >> ((j & 1) * 16)));
}

// 8-element row load (f32 fallback path); also returns raw f16 pairs
__device__ __forceinline__ void loadc8r(bool f32, const void* p, size_t off, float o[8], uint4& raw) {
    if (f32) {
        const float* q = (const float*)p + off;
        float4 a = *(const float4*)q;
        float4 b = *(const float4*)(q + 4);
        o[0] = a.x; o[1] = a.y; o[2] = a.z; o[3] = a.w;
        o[4] = b.x; o[5] = b.y; o[6] = b.z; o[7] = b.w;
        raw.x = pkrtz(a.x, a.y); raw.y = pkrtz(a.z, a.w);
        raw.z = pkrtz(b.x, b.y); raw.w = pkrtz(b.z, b.w);
    } else {
        uint4 v = *(const uint4*)((const ushortT*)p + off);
        raw = v;
        unpack8(v, o);
    }
}

// ---------------- combined weight build (all 3 layers in ONE launch) + ghist zeroing ----------------
__global__ __launch_bounds__(256) void build_wc3(
    const float* __restrict__ Ws0, const float* __restrict__ Wb0, ushortT* __restrict__ Wc0,
    const float* __restrict__ Ws1, const float* __restrict__ Wb1, ushortT* __restrict__ Wc1,
    const float* __restrict__ Ws2, const float* __restrict__ Wb2, ushortT* __restrict__ Wc2,
    int* __restrict__ ghist) {
    int b = blockIdx.x;
    if (b >= 993) {
        int i = (b - 993) * 256 + threadIdx.x;
        if (i < 512) ghist[i] = 0;
        return;
    }
    const float *Ws, *Wb;
    ushortT* Wc;
    int dout, din, base;
    if (b < 320) { Ws = Ws0; Wb = Wb0; Wc = Wc0; dout = 128; din = 128; base = b; }
    else if (b < 640) { Ws = Ws1; Wb = Wb1; Wc = Wc1; dout = 128; din = 128; base = b - 320; }
    else { Ws = Ws2; Wb = Wb2; Wc = Wc2; dout = 47; din = 384; base = b - 640; }
    int idx = base * 256 + threadIdx.x;
    int kw = 5 * din;
    if (idx >= dout * kw) return;
    int n = idx / kw, c = idx % kw;
    float v;
    if (c < 4 * din) {
        int seg = c >> 9;
        int rem = c & 511;
        int g = rem >> 7;
        int dl = rem & 127;
        v = Ws[(size_t)n * 4 * din + 4 * (seg * 128 + dl) + g];
    } else {
        v = Wb[(size_t)n * din + (c - 4 * din)];
    }
    Wc[idx] = f2h(v);
}

// ---------------- per-row LN stats for f32 x (+ optional f16 mirror) ----------------

__global__ __launch_bounds__(256) void stats_f32(const float* __restrict__ X, float2* __restrict__ ST,
                                                 ushortT* __restrict__ xb, int n) {
    int wid = (blockIdx.x * 256 + threadIdx.x) >> 6;
    int lane = threadIdx.x & 63;
    if (wid >= n) return;
    float2 v = *(const float2*)(X + (size_t)wid * 128 + lane * 2);
    if (xb) {
        *(unsigned*)(xb + (size_t)wid * 128 + lane * 2) = pkrtz(v.x, v.y);
    }
    float s = v.x + v.y, ss = v.x * v.x + v.y * v.y;
    #pragma unroll
    for (int d = 1; d < 64; d <<= 1) { s += __shfl_xor(s, d); ss += __shfl_xor(ss, d); }
    if (lane == 0) ST[wid] = make_float2(s, ss);
}

// ---------------- CSR build: two-level counting sort ----------------

__device__ __forceinline__ int wave_incl_scan(int v, int lane) {
    #pragma unroll
    for (int d = 1; d < 64; d <<= 1) {
        int o = __shfl_up(v, d);
        if (lane >= d) v += o;
    }
    return v;
}

__global__ __launch_bounds__(256) void coarse_hist(const int* __restrict__ dst, int* __restrict__ ghist,
                                                   int E, int nb) {
    __shared__ int h[512];
    for (int i = threadIdx.x; i < 512; i += 256) h[i] = 0;
    __syncthreads();
    int stride = gridDim.x * 256;
    for (int e = blockIdx.x * 256 + threadIdx.x; e < E; e += stride) {
        atomicAdd(&h[dst[e] >> 8], 1);
    }
    __syncthreads();
    for (int i = threadIdx.x; i < nb; i += 256) {
        int c = h[i];
        if (c) atomicAdd(&ghist[i], c);
    }
}

__global__ __launch_bounds__(64) void bucket_scan(const int* __restrict__ ghist, int* __restrict__ base,
                                                  int* __restrict__ gcur, int nb) {
    int lane = threadIdx.x;
    int carry = 0;
    for (int b0 = 0; b0 < nb; b0 += 64) {
        int i = b0 + lane;
        int v = (i < nb) ? ghist[i] : 0;
        int incl = wave_incl_scan(v, lane);
        if (i < nb) { int ex = carry + incl - v; base[i] = ex; gcur[i] = ex; }
        carry += __shfl(incl, 63);
    }
    if (lane == 0) base[nb] = carry;
}

#define SCAT_CH 4096
__global__ __launch_bounds__(256) void coarse_scatter(const int* __restrict__ src, const int* __restrict__ dst,
                                                      int* __restrict__ gcur, unsigned* __restrict__ pairs,
                                                      int E, int nb) {
    __shared__ int cur[512];
    for (int i = threadIdx.x; i < 512; i += 256) cur[i] = 0;
    __syncthreads();
    int e0 = blockIdx.x * SCAT_CH;
    int e1 = min(e0 + SCAT_CH, E);
    for (int e = e0 + threadIdx.x; e < e1; e += 256) atomicAdd(&cur[dst[e] >> 8], 1);
    __syncthreads();
    for (int i = threadIdx.x; i < nb; i += 256) {
        int c = cur[i];
        cur[i] = c ? atomicAdd(&gcur[i], c) : 0;
    }
    __syncthreads();
    for (int e = e0 + threadIdx.x; e < e1; e += 256) {
        int d = dst[e];
        int r = atomicAdd(&cur[d >> 8], 1);
        pairs[r] = (unsigned)src[e] | ((unsigned)(d & 255) << 24);
    }
}

__global__ __launch_bounds__(256) void fine_csr(const unsigned* __restrict__ pairs, const int* __restrict__ base,
                                                int* __restrict__ rowptr, int* __restrict__ colv,
                                                float* __restrict__ dinv, int n, int E) {
    __shared__ int h[256];
    __shared__ int cur[256];
    __shared__ int wt[4];
    int b = blockIdx.x, tid = threadIdx.x;
    int e0 = base[b], e1 = base[b + 1];
    h[tid] = 0;
    __syncthreads();
    for (int e = e0 + tid; e < e1; e += 256) atomicAdd(&h[pairs[e] >> 24], 1);
    __syncthreads();
    int v = h[tid];
    int lane = tid & 63, w = tid >> 6;
    int incl = wave_incl_scan(v, lane);
    if (lane == 63) wt[w] = incl;
    __syncthreads();
    int woff = 0;
    for (int i = 0; i < w; i++) woff += wt[i];
    int excl = woff + incl - v;
    int node = b * 256 + tid;
    if (node < n) {
        rowptr[node] = e0 + excl;
        dinv[node] = rsqrtf((float)(v + 1));  // +1 self loop
        if (node == n - 1) rowptr[n] = E;
    }
    cur[tid] = e0 + excl;
    __syncthreads();
    for (int e = e0 + tid; e < e1; e += 256) {
        unsigned p = pairs[e];
        int r = atomicAdd(&cur[p >> 24], 1);
        colv[r] = (int)(p & 0x00FFFFFFu);
    }
}

// ---------------- fused gather + FastKAN transform ----------------
// Template: GSEG = segment sourced from an in-block GATHER (phase 1), -1 = plain fkan.
// WG = write gathered rows + stats to global (needed when a later layer consumes them).
// Phase 1 (GSEG>=0): each block gathers the 64 rows it will transform, byte-identical
//   to the old agg128 (same lane layout, same edge order, same f2h rounding) -> rows go
//   to LDS (row stride 136 f16, +8 pad to break the 256B bank cycle) + optionally global.
// Phase 2: r9 fkan body (2 panels x 2 K-halves, packed-f16 math, ring prefetch for
//   NSEG==1 global input); gathered segment reads come from LDS; its LN stats from stg.
// The red reduction buffer ALIASES the gather buffer -> extra barrier after chunk loop.
template <int NSEG, int DOUT, int F32MASK, int GSEG, bool WG>
__global__ __launch_bounds__(256) void fkan_kernel(
    const void* __restrict__ X0, int s0,
    const void* __restrict__ X1, int s1,
    const void* __restrict__ X2, int s2,
    const float2* __restrict__ ST0, const float2* __restrict__ ST1, const float2* __restrict__ ST2,
    const float* __restrict__ lng, const float* __restrict__ lnb,
    const ushortT* __restrict__ Wc,
    const float* __restrict__ bs, const float* __restrict__ bb,
    const float* __restrict__ dinv,
    ushortT* __restrict__ H, int hstride, int nrows,
    const ushortT* __restrict__ Hsrc, const float* __restrict__ bgg,
    const int* __restrict__ rowptr, const int* __restrict__ colv,
    ushortT* __restrict__ Aout, float2* __restrict__ STout) {
    constexpr int DIN = NSEG * 128;
    constexpr int KW = 5 * DIN;
    constexpr int NT = (DOUT + 15) / 16;
    constexpr int NCH = NSEG * 2;           // chunks per K-half
    constexpr bool RING = (GSEG < 0) && (F32MASK == 0) && (NSEG == 1);
    constexpr int GROW = 136;               // f16 per gathered LDS row (128 + 8 pad)
    constexpr int GBUFB = 64 * GROW * 2;
    constexpr int REDB = 2 * NT * 4 * 64 * 4;
    constexpr int HEADB = (GSEG >= 0) ? (GBUFB > REDB ? GBUFB : REDB) : REDB;
    constexpr int SMEMB = HEADB + ((GSEG >= 0) ? 512 : 0);
    __shared__ __align__(16) char smem[SMEMB];
    float* red = (float*)smem;       // [2][NT][4][64] f32
    ushortT* glds = (ushortT*)smem;  // [64][GROW] f16 (aliases red; barrier-separated)
    float2* stg = (float2*)(smem + HEADB);

    int tid = threadIdx.x;
    int w = tid >> 6, lane = tid & 63;

    // ---- phase 1: gather own 64 rows (agg128-identical math) ----
    if (GSEG >= 0) {
        int gg = lane >> 4, tt = lane & 15;
        float4 b0 = *(const float4*)(bgg + tt * 8);
        float4 b1 = *(const float4*)(bgg + tt * 8 + 4);
        float bgs[8] = {b0.x, b0.y, b0.z, b0.w, b1.x, b1.y, b1.z, b1.w};
        for (int k = 0; k < 16; k++) {
            int nd = blockIdx.x * 64 + w * 16 + k;
            if (nd >= nrows) break;
            float di = dinv[nd];
            float a[8] = {0.f, 0.f, 0.f, 0.f, 0.f, 0.f, 0.f, 0.f};
            if (gg == 0) unpack_add(*(const uint4*)(Hsrc + (size_t)nd * 128 + tt * 8), a);  // self
            int e0 = rowptr[nd], e1 = rowptr[nd + 1];
            int e = e0 + gg;
            for (; e + 4 < e1; e += 8) {
                int s0i = colv[e], s1i = colv[e + 4];
                uint4 v0 = *(const uint4*)(Hsrc + (size_t)s0i * 128 + tt * 8);
                uint4 v1 = *(const uint4*)(Hsrc + (size_t)s1i * 128 + tt * 8);
                unpack_add(v0, a);
                unpack_add(v1, a);
            }
            if (e < e1) unpack_add(*(const uint4*)(Hsrc + (size_t)colv[e] * 128 + tt * 8), a);
            #pragma unroll
            for (int j = 0; j < 8; j++) {
                a[j] += __shfl_xor(a[j], 16);
                a[j] += __shfl_xor(a[j], 32);
            }
            if (gg == 0) {
                unsigned rb[8];
                float s = 0.f, ss = 0.f;
                #pragma unroll
                for (int j = 0; j < 8; j++) {
                    float o = di * a[j] + bgs[j];
                    rb[j] = f2h(o);
                    float back = h2f((unsigned short)rb[j]);
                    s += back; ss += back * back;   // stats of STORED values
                }
                uint4 pk;
                pk.x = rb[0] | (rb[1] << 16);
                pk.y = rb[2] | (rb[3] << 16);
                pk.z = rb[4] | (rb[5] << 16);
                pk.w = rb[6] | (rb[7] << 16);
                *(uint4*)(glds + (w * 16 + k) * GROW + tt * 8) = pk;
                if (WG) *(uint4*)(Aout + (size_t)nd * 128 + tt * 8) = pk;
                #pragma unroll
                for (int d = 1; d < 16; d <<= 1) { s += __shfl_xor(s, d); ss += __shfl_xor(ss, d); }
                if (tt == 0) {
                    stg[w * 16 + k] = make_float2(s, ss);
                    if (WG) STout[nd] = make_float2(s, ss);
                }
            }
        }
        __syncthreads();
    }

    // ---- phase 2: fkan transform ----
    int m = lane & 15, q = lane >> 4;
    int r = w & 1;    // row panel
    int kk = w >> 1;  // K half
    int baseA = blockIdx.x * 64 + r * 16;
    int baseB = baseA + 32;
    int rA = min(baseA + m, nrows - 1);
    int rB = min(baseB + m, nrows - 1);

    float muA, scA, muB, scB;
    {
        float sum, ssq;
        if (GSEG < 0) {
            float2 st = ST0[rA]; sum = st.x; ssq = st.y;
            if (NSEG == 3) { float2 t1 = ST1[rA]; sum += t1.x; ssq += t1.y; float2 t2 = ST2[rA]; sum += t2.x; ssq += t2.y; }
        } else if (NSEG == 1) {
            float2 sg = stg[rA - blockIdx.x * 64]; sum = sg.x; ssq = sg.y;
        } else {  // NSEG==3, GSEG==2
            float2 st = ST0[rA]; float2 t1 = ST1[rA]; float2 sg = stg[rA - blockIdx.x * 64];
            sum = st.x + t1.x + sg.x; ssq = st.y + t1.y + sg.y;
        }
        muA = sum * (1.0f / DIN);
        float var = ssq * (1.0f / DIN) - muA * muA;
        scA = rsqrtf(fmaxf(var, 0.0f) + 1e-5f);
    }
    {
        float sum, ssq;
        if (GSEG < 0) {
            float2 st = ST0[rB]; sum = st.x; ssq = st.y;
            if (NSEG == 3) { float2 t1 = ST1[rB]; sum += t1.x; ssq += t1.y; float2 t2 = ST2[rB]; sum += t2.x; ssq += t2.y; }
        } else if (NSEG == 1) {
            float2 sg = stg[rB - blockIdx.x * 64]; sum = sg.x; ssq = sg.y;
        } else {
            float2 st = ST0[rB]; float2 t1 = ST1[rB]; float2 sg = stg[rB - blockIdx.x * 64];
            sum = st.x + t1.x + sg.x; ssq = st.y + t1.y + sg.y;
        }
        muB = sum * (1.0f / DIN);
        float var = ssq * (1.0f / DIN) - muB * muB;
        scB = rsqrtf(fmaxf(var, 0.0f) + 1e-5f);
    }

    float4v acc[NT][2];
    #pragma unroll
    for (int t = 0; t < NT; t++) {
        acc[t][0] = (float4v){0.f, 0.f, 0.f, 0.f};
        acc[t][1] = (float4v){0.f, 0.f, 0.f, 0.f};
    }

    const float CC = 0.90084159f;  // 0.75*sqrt(log2 e): exp(-((z-G)*.75)^2)=exp2(-(z*CC-G*CC)^2)
    const __half2 Gc2[4] = {
        __float2half2_rn(-2.f * CC), __float2half2_rn(-2.f / 3.f * CC),
        __float2half2_rn(2.f / 3.f * CC), __float2half2_rn(2.f * CC)};
    const __half2 NL2E = __float2half2_rn(-1.44269504f);
    const __half2 ONE2 = __float2half2_rn(1.0f);

    uint4 rawA[2], rawB[2];
    if (RING) {
        int d00 = kk * 32 + q * 8;  // h=0: seg=0, i=kk
        rawA[0] = *(const uint4*)((const ushortT*)X0 + (size_t)rA * s0 + d00);
        rawB[0] = *(const uint4*)((const ushortT*)X0 + (size_t)rB * s0 + d00);
    }

    #pragma unroll
    for (int h = 0; h < NCH; h++) {
        const int seg = h >> 1;
        int i = 2 * (h & 1) + kk;
        int d0 = i * 32 + q * 8;
        float xa[8], xb8[8];
        uint4 curA, curB;
        if (GSEG >= 0 && seg == GSEG) {
            curA = *(const uint4*)(glds + (size_t)(rA - blockIdx.x * 64) * GROW + d0);
            curB = *(const uint4*)(glds + (size_t)(rB - blockIdx.x * 64) * GROW + d0);
            unpack8(curA, xa);
            unpack8(curB, xb8);
        } else if (RING) {
            if (h + 1 < NCH) {
                int i2 = 2 * ((h + 1) & 1) + kk;
                int d2 = i2 * 32 + q * 8;
                rawA[(h + 1) & 1] = *(const uint4*)((const ushortT*)X0 + (size_t)rA * s0 + d2);
                rawB[(h + 1) & 1] = *(const uint4*)((const ushortT*)X0 + (size_t)rB * s0 + d2);
            }
            curA = rawA[h & 1];
            curB = rawB[h & 1];
            unpack8(curA, xa);
            unpack8(curB, xb8);
        } else {
            const void* Xp = (seg == 0) ? X0 : (seg == 1) ? X1 : X2;
            int str = (seg == 0) ? s0 : (seg == 1) ? s1 : s2;
            bool f32 = ((F32MASK >> seg) & 1) != 0;
            loadc8r(f32, Xp, (size_t)rA * str + d0, xa, curA);
            loadc8r(f32, Xp, (size_t)rB * str + d0, xb8, curB);
        }
        float4 gv0 = *(const float4*)(lng + seg * 128 + d0);
        float4 gv1 = *(const float4*)(lng + seg * 128 + d0 + 4);
        float4 bv0 = *(const float4*)(lnb + seg * 128 + d0);
        float4 bv1 = *(const float4*)(lnb + seg * 128 + d0 + 4);
        float gvs[8] = {gv0.x, gv0.y, gv0.z, gv0.w, gv1.x, gv1.y, gv1.z, gv1.w};
        float bvs[8] = {bv0.x, bv0.y, bv0.z, bv0.w, bv1.x, bv1.y, bv1.z, bv1.w};
        float za[8], zb[8];
        #pragma unroll
        for (int j = 0; j < 8; j++) {
            za[j] = (xa[j] - muA) * scA * gvs[j] + bvs[j];
            zb[j] = (xb8[j] - muB) * scB * gvs[j] + bvs[j];
        }
        __half2 zhA[4], zhB[4];
        #pragma unroll
        for (int p = 0; p < 4; p++) {
            zhA[p] = __builtin_bit_cast(__half2, pkrtz(za[2 * p] * CC, za[2 * p + 1] * CC));
            zhB[p] = __builtin_bit_cast(__half2, pkrtz(zb[2 * p] * CC, zb[2 * p + 1] * CC));
        }
        // RBF: 4 grid points, packed f16; exp output IS the fragment pair
        #pragma unroll
        for (int g = 0; g < 4; g++) {
            uint4v ua, ub;
            #pragma unroll
            for (int p = 0; p < 4; p++) {
                __half2 dA = __hsub2(zhA[p], Gc2[g]);
                ua[p] = __builtin_bit_cast(unsigned, h2exp2(__hmul2(dA, __hneg2(dA))));
                __half2 dB = __hsub2(zhB[p], Gc2[g]);
                ub[p] = __builtin_bit_cast(unsigned, h2exp2(__hmul2(dB, __hneg2(dB))));
            }
            f16x8 afa = __builtin_bit_cast(f16x8, ua);
            f16x8 afb = __builtin_bit_cast(f16x8, ub);
            int kbase = seg * 512 + g * 128 + i * 32;
            #pragma unroll
            for (int t = 0; t < NT; t++) {
                int n = t * 16 + m;
                f16x8 bfr = (f16x8)(_Float16)0;
                if ((DOUT % 16 == 0) || (n < DOUT))
                    bfr = *(const f16x8*)(Wc + (size_t)n * KW + kbase + q * 8);
                acc[t][0] = __builtin_amdgcn_mfma_f32_16x16x32_f16(afa, bfr, acc[t][0], 0, 0, 0);
                acc[t][1] = __builtin_amdgcn_mfma_f32_16x16x32_f16(afb, bfr, acc[t][1], 0, 0, 0);
            }
        }
        // SiLU from raw f16 pairs: x * 1/(1 + exp2(-x*log2e))
        {
            unsigned raA[4] = {curA.x, curA.y, curA.z, curA.w};
            unsigned raB[4] = {curB.x, curB.y, curB.z, curB.w};
            uint4v ua, ub;
            #pragma unroll
            for (int p = 0; p < 4; p++) {
                __half2 xhA = __builtin_bit_cast(__half2, raA[p]);
                __half2 sgA = h2rcp(__hadd2(ONE2, h2exp2(__hmul2(xhA, NL2E))));
                ua[p] = __builtin_bit_cast(unsigned, __hmul2(xhA, sgA));
                __half2 xhB = __builtin_bit_cast(__half2, raB[p]);
                __half2 sgB = h2rcp(__hadd2(ONE2, h2exp2(__hmul2(xhB, NL2E))));
                ub[p] = __builtin_bit_cast(unsigned, __hmul2(xhB, sgB));
            }
            f16x8 afa = __builtin_bit_cast(f16x8, ua);
            f16x8 afb = __builtin_bit_cast(f16x8, ub);
            int kbase = 4 * DIN + seg * 128 + i * 32;
            #pragma unroll
            for (int t = 0; t < NT; t++) {
                int n = t * 16 + m;
                f16x8 bfr = (f16x8)(_Float16)0;
                if ((DOUT % 16 == 0) || (n < DOUT))
                    bfr = *(const f16x8*)(Wc + (size_t)n * KW + kbase + q * 8);
                acc[t][0] = __builtin_amdgcn_mfma_f32_16x16x32_f16(afa, bfr, acc[t][0], 0, 0, 0);
                acc[t][1] = __builtin_amdgcn_mfma_f32_16x16x32_f16(afb, bfr, acc[t][1], 0, 0, 0);
            }
        }
    }

    // red aliases glds: make sure all LDS reads of gathered rows are done first
    if (GSEG >= 0) __syncthreads();

    // ---- cross-wave K-half reduction (2 barriers, self-ordered LDS reuse) ----
    if (kk == 1) {
        #pragma unroll
        for (int t = 0; t < NT; t++)
            #pragma unroll
            for (int j = 0; j < 4; j++) red[((r * NT + t) * 4 + j) * 64 + lane] = acc[t][0][j];
    }
    __syncthreads();
    if (kk == 0) {
        #pragma unroll
        for (int t = 0; t < NT; t++)
            #pragma unroll
            for (int j = 0; j < 4; j++) {
                acc[t][0][j] += red[((r * NT + t) * 4 + j) * 64 + lane];  // full group-A sum
                red[((r * NT + t) * 4 + j) * 64 + lane] = acc[t][1][j];   // hand B partial over
            }
    }
    __syncthreads();
    if (kk == 1) {
        #pragma unroll
        for (int t = 0; t < NT; t++)
            #pragma unroll
            for (int j = 0; j < 4; j++) acc[t][1][j] += red[((r * NT + t) * 4 + j) * 64 + lane];
    }

    // ---- epilogue: kk=0 stores group A, kk=1 stores group B (C/D: col=lane&15, row=q*4+j) ----
    int gbase = (kk == 0) ? baseA : baseB;
    float dd[4];
    #pragma unroll
    for (int j = 0; j < 4; j++) {
        int row = gbase + q * 4 + j;
        dd[j] = (row < nrows) ? dinv[row] : 0.f;
    }
    if (kk == 0) {
        #pragma unroll
        for (int t = 0; t < NT; t++) {
            int col = t * 16 + m;
            if ((DOUT % 16 == 0) || (col < DOUT)) {
                float bias = bs[col] + bb[col];
                #pragma unroll
                for (int j = 0; j < 4; j++) {
                    int row = gbase + q * 4 + j;
                    if (row < nrows) H[(size_t)row * hstride + col] = f2h((acc[t][0][j] + bias) * dd[j]);
                }
            }
        }
    } else {
        #pragma unroll
        for (int t = 0; t < NT; t++) {
            int col = t * 16 + m;
            if ((DOUT % 16 == 0) || (col < DOUT)) {
                float bias = bs[col] + bb[col];
                #pragma unroll
                for (int j = 0; j < 4; j++) {
                    int row = gbase + q * 4 + j;
                    if (row < nrows) H[(size_t)row * hstride + col] = f2h((acc[t][1][j] + bias) * dd[j]);
                }
            }
        }
    }
}

// ---------------- final aggregation (H stride 64, cols 47..63 junk). 16 edge-streams. ----------------
__global__ __launch_bounds__(256) void agg47_kernel(
    const ushortT* __restrict__ H, float* __restrict__ OUT,
    const float* __restrict__ bg, const int* __restrict__ rowptr,
    const int* __restrict__ colv, const float* __restrict__ dinv, int n) {
    int wid = (blockIdx.x * 256 + threadIdx.x) >> 6;
    int lane = threadIdx.x & 63;
    if (wid >= n) return;
    int g = lane >> 3, t = lane & 7;
    float di = dinv[wid];
    float a[8] = {0.f, 0.f, 0.f, 0.f, 0.f, 0.f, 0.f, 0.f};
    if (g == 0) unpack_add(*(const uint4*)(H + (size_t)wid * 64 + t * 8), a);  // self
    int e0 = rowptr[wid], e1 = rowptr[wid + 1];
    int e = e0 + g;
    for (; e + 8 < e1; e += 16) {
        int s0i = colv[e], s1i = colv[e + 8];
        uint4 v0 = *(const uint4*)(H + (size_t)s0i * 64 + t * 8);
        uint4 v1 = *(const uint4*)(H + (size_t)s1i * 64 + t * 8);
        unpack_add(v0, a);
        unpack_add(v1, a);
    }
    if (e < e1) {
        unpack_add(*(const uint4*)(H + (size_t)colv[e] * 64 + t * 8), a);
    }
    #pragma unroll
    for (int j = 0; j < 8; j++) {
        a[j] += __shfl_xor(a[j], 8);
        a[j] += __shfl_xor(a[j], 16);
        a[j] += __shfl_xor(a[j], 32);
    }
    if (g == 0) {
        #pragma unroll
        for (int j = 0; j < 8; j++) {
            int c = t * 8 + j;
            if (c < 47) OUT[(size_t)wid * 47 + c] = di * a[j] + bg[c];
        }
    }
}

// ---------------- launcher ----------------

extern "C" void kernel_launch(void* const* d_in, const int* in_sizes, int n_in,
                              void* d_out, int out_size, void* d_ws, size_t ws_size,
                              hipStream_t stream) {
    const float* x = (const float*)d_in[0];
    const int* ei = (const int*)d_in[1];
    const float* lng0 = (const float*)d_in[2];
    const float* lnb0 = (const float*)d_in[3];
    const float* Ws0 = (const float*)d_in[4];
    const float* bs0 = (const float*)d_in[5];
    const float* Wb0 = (const float*)d_in[6];
    const float* bb0 = (const float*)d_in[7];
    const float* bg0 = (const float*)d_in[8];
    const float* lng1 = (const float*)d_in[9];
    const float* lnb1 = (const float*)d_in[10];
    const float* Ws1 = (const float*)d_in[11];
    const float* bs1 = (const float*)d_in[12];
    const float* Wb1 = (const float*)d_in[13];
    const float* bb1 = (const float*)d_in[14];
    const float* bg1 = (const float*)d_in[15];
    const float* lng2 = (const float*)d_in[16];
    const float* lnb2 = (const float*)d_in[17];
    const float* Ws2 = (const float*)d_in[18];
    const float* bs2 = (const float*)d_in[19];
    const float* Wb2 = (const float*)d_in[20];
    const float* bb2 = (const float*)d_in[21];
    const float* bg2 = (const float*)d_in[22];

    const int N = in_sizes[0] / 128;
    const int E = in_sizes[1] / 2;
    const int NB = (N + 255) >> 8;  // coarse buckets of 256 nodes (requires N < 2^24)

    char* wsp = (char*)d_ws;
    size_t off = 0;
    auto alloc = [&](size_t bytes) {
        off = (off + 255) & ~(size_t)255;
        void* p = wsp + off;
        off += bytes;
        return p;
    };
    int* ghist = (int*)alloc(512 * 4);
    int* bbase = (int*)alloc(513 * 4);
    int* gcur = (int*)alloc(512 * 4);
    int* rowptr = (int*)alloc((size_t)(N + 1) * 4);
    int* colv = (int*)alloc((size_t)E * 4);
    float* dinvv = (float*)alloc((size_t)N * 4);
    ushortT* hbuf = (ushortT*)alloc((size_t)N * 128 * 2);   // H1, later H3 (stride 64)
    ushortT* a1 = (ushortT*)alloc((size_t)N * 128 * 2);     // gathered layer-1 output
    ushortT* a2 = (ushortT*)alloc((size_t)N * 128 * 2);     // H2 (layer-2 transform output)
    float2* stx = (float2*)alloc((size_t)N * 8);
    float2* st1 = (float2*)alloc((size_t)N * 8);
    float2* st2 = (float2*)alloc((size_t)N * 8);            // unused now (kept for layout)
    ushortT* Wc0 = (ushortT*)alloc((size_t)128 * 640 * 2);
    ushortT* Wc1 = (ushortT*)alloc((size_t)128 * 640 * 2);
    ushortT* Wc2 = (ushortT*)alloc((size_t)47 * 1920 * 2);
    size_t off_base = off;
    ushortT* xb = (ushortT*)alloc((size_t)N * 128 * 2);  // f16 mirror of x
    bool fits = (off <= ws_size);
    if (!fits) off = off_base;
    (void)n_in; (void)out_size; (void)st2;

    // pairs staging aliases hbuf: pairs is dead before the first fkan writes hbuf.
    unsigned* pairs = (unsigned*)hbuf;

    const int* srcp = ei;
    const int* dstp = ei + E;

    int gF = (N + 63) / 64;
    int gW = (N + 3) / 4;
    int gScat = (E + SCAT_CH - 1) / SCAT_CH;

    // single launch: all three Wc builds + ghist zeroing (993 + 2 blocks)
    build_wc3<<<995, 256, 0, stream>>>(Ws0, Wb0, Wc0, Ws1, Wb1, Wc1, Ws2, Wb2, Wc2, ghist);

    // CSR build
    coarse_hist<<<NB, 256, 0, stream>>>(dstp, ghist, E, NB);
    bucket_scan<<<1, 64, 0, stream>>>(ghist, bbase, gcur, NB);
    coarse_scatter<<<gScat, 256, 0, stream>>>(srcp, dstp, gcur, pairs, E, NB);
    fine_csr<<<NB, 256, 0, stream>>>(pairs, bbase, rowptr, colv, dinvv, N, E);

    stats_f32<<<gW, 256, 0, stream>>>(x, stx, fits ? xb : nullptr, N);

    // layer 1: transform x -> H1 (hbuf, stride 128)
    if (fits)
        fkan_kernel<1, 128, 0, -1, false><<<gF, 256, 0, stream>>>(
            xb, 128, xb, 128, xb, 128, stx, stx, stx, lng0, lnb0, Wc0, bs0, bb0, dinvv,
            hbuf, 128, N, nullptr, nullptr, nullptr, nullptr, nullptr, nullptr);
    else
        fkan_kernel<1, 128, 1, -1, false><<<gF, 256, 0, stream>>>(
            x, 128, x, 128, x, 128, stx, stx, stx, lng0, lnb0, Wc0, bs0, bb0, dinvv,
            hbuf, 128, N, nullptr, nullptr, nullptr, nullptr, nullptr, nullptr);

    // layer 2 fused: gather H1 -> a1 (global, + st1), transform -> H2 (a2, stride 128)
    fkan_kernel<1, 128, 0, 0, true><<<gF, 256, 0, stream>>>(
        nullptr, 128, nullptr, 128, nullptr, 128, nullptr, nullptr, nullptr,
        lng1, lnb1, Wc1, bs1, bb1, dinvv, a2, 128, N,
        hbuf, bg0, rowptr, colv, a1, st1);

    // layer 3 fused: gather H2 -> LDS only (a2-rows + st2 stay in-block), transform -> H3 (hbuf, stride 64)
    if (fits)
        fkan_kernel<3, 47, 0, 2, false><<<gF, 256, 0, stream>>>(
            xb, 128, a1, 128, nullptr, 128, stx, st1, nullptr,
            lng2, lnb2, Wc2, bs2, bb2, dinvv, hbuf, 64, N,
            a2, bg1, rowptr, colv, nullptr, nullptr);
    else
        fkan_kernel<3, 47, 1, 2, false><<<gF, 256, 0, stream>>>(
            x, 128, a1, 128, nullptr, 128, stx, st1, nullptr,
            lng2, lnb2, Wc2, bs2, bb2, dinvv, hbuf, 64, N,
            a2, bg1, rowptr, colv, nullptr, nullptr);

    agg47_kernel<<<gW, 256, 0, stream>>>(hbuf, (float*)d_out, bg2, rowptr, colv, dinvv, N);
}

// Round 11
// 697.142 us; speedup vs baseline: 1.1815x; 1.1815x over previous
//
#include <hip/hip_runtime.h>
#include <hip/hip_fp16.h>

typedef unsigned short ushortT;
typedef _Float16 f16x8 __attribute__((ext_vector_type(8)));
typedef __attribute__((ext_vector_type(4))) float float4v;
typedef __attribute__((ext_vector_type(4))) unsigned int uint4v;

__device__ __forceinline__ unsigned short f2h(float f) {  // RTNE f32->f16 (v_cvt_f16_f32)
    _Float16 h = (_Float16)f;
    return __builtin_bit_cast(unsigned short, h);
}
__device__ __forceinline__ float h2f(unsigned short b) {  // v_cvt_f32_f16
    return (float)__builtin_bit_cast(_Float16, b);
}
// packed f32x2 -> f16x2, RTZ (v_cvt_pkrtz_f16_f32, 1 inst).
__device__ __forceinline__ unsigned pkrtz(float lo, float hi) {
    auto h = __builtin_amdgcn_cvt_pkrtz(lo, hi);
    return __builtin_bit_cast(unsigned, h);
}
__device__ __forceinline__ void unpack8(uint4 v, float o[8]) {
    unsigned uu[4] = {v.x, v.y, v.z, v.w};
    #pragma unroll
    for (int j = 0; j < 8; j++) o[j] = h2f((unsigned short)(uu[j >> 1] >> ((j & 1) * 16)));
}
__device__ __forceinline__ void unpack_add(uint4 v, float a[8]) {  // f16 pairs
    unsigned uu[4] = {v.x, v.y, v.z, v.w};
    #pragma unroll
    for (int j = 0; j < 8; j++) a[j] += h2f((unsigned short)(uu[j >> 1] >> ((j & 1) * 16)));
}

// 8-element row load (f32 fallback path); also returns raw f16 pairs
__device__ __forceinline__ void loadc8r(bool f32, const void* p, size_t off, float o[8], uint4& raw) {
    if (f32) {
        const float* q = (const float*)p + off;
        float4 a = *(const float4*)q;
        float4 b = *(const float4*)(q + 4);
        o[0] = a.x; o[1] = a.y; o[2] = a.z; o[3] = a.w;
        o[4] = b.x; o[5] = b.y; o[6] = b.z; o[7] = b.w;
        raw.x = pkrtz(a.x, a.y); raw.y = pkrtz(a.z, a.w);
        raw.z = pkrtz(b.x, b.y); raw.w = pkrtz(b.z, b.w);
    } else {
        uint4 v = *(const uint4*)((const ushortT*)p + off);
        raw = v;
        unpack8(v, o);
    }
}

// ---------------- combined weight build (all 3 layers in ONE launch) + ghist zeroing ----------------
// Wc[n][seg*512+g*128+dl | 4*DIN+d] (f16). Grid: [0,320) L0, [320,640) L1, [640,993) L2,
// [993,995) zero ghist (folds the zero_ints launch away).
__global__ __launch_bounds__(256) void build_wc3(
    const float* __restrict__ Ws0, const float* __restrict__ Wb0, ushortT* __restrict__ Wc0,
    const float* __restrict__ Ws1, const float* __restrict__ Wb1, ushortT* __restrict__ Wc1,
    const float* __restrict__ Ws2, const float* __restrict__ Wb2, ushortT* __restrict__ Wc2,
    int* __restrict__ ghist) {
    int b = blockIdx.x;
    if (b >= 993) {
        int i = (b - 993) * 256 + threadIdx.x;
        if (i < 512) ghist[i] = 0;
        return;
    }
    const float *Ws, *Wb;
    ushortT* Wc;
    int dout, din, base;
    if (b < 320) { Ws = Ws0; Wb = Wb0; Wc = Wc0; dout = 128; din = 128; base = b; }
    else if (b < 640) { Ws = Ws1; Wb = Wb1; Wc = Wc1; dout = 128; din = 128; base = b - 320; }
    else { Ws = Ws2; Wb = Wb2; Wc = Wc2; dout = 47; din = 384; base = b - 640; }
    int idx = base * 256 + threadIdx.x;
    int kw = 5 * din;
    if (idx >= dout * kw) return;
    int n = idx / kw, c = idx % kw;
    float v;
    if (c < 4 * din) {
        int seg = c >> 9;
        int rem = c & 511;
        int g = rem >> 7;
        int dl = rem & 127;
        v = Ws[(size_t)n * 4 * din + 4 * (seg * 128 + dl) + g];
    } else {
        v = Wb[(size_t)n * din + (c - 4 * din)];
    }
    Wc[idx] = f2h(v);
}

// ---------------- per-row LN stats for f32 x (+ optional f16 mirror) ----------------

__global__ __launch_bounds__(256) void stats_f32(const float* __restrict__ X, float2* __restrict__ ST,
                                                 ushortT* __restrict__ xb, int n) {
    int wid = (blockIdx.x * 256 + threadIdx.x) >> 6;
    int lane = threadIdx.x & 63;
    if (wid >= n) return;
    float2 v = *(const float2*)(X + (size_t)wid * 128 + lane * 2);
    if (xb) {
        *(unsigned*)(xb + (size_t)wid * 128 + lane * 2) = pkrtz(v.x, v.y);
    }
    float s = v.x + v.y, ss = v.x * v.x + v.y * v.y;
    #pragma unroll
    for (int d = 1; d < 64; d <<= 1) { s += __shfl_xor(s, d); ss += __shfl_xor(ss, d); }
    if (lane == 0) ST[wid] = make_float2(s, ss);
}

// ---------------- CSR build: two-level counting sort ----------------
// Pack: src (bits 0..23, N < 2^24) | (dst & 255) << 24. Coarse bucket = dst >> 8.

__device__ __forceinline__ int wave_incl_scan(int v, int lane) {
    #pragma unroll
    for (int d = 1; d < 64; d <<= 1) {
        int o = __shfl_up(v, d);
        if (lane >= d) v += o;
    }
    return v;
}

// coarse histogram of dst>>8 (LDS-staged; ~nb global atomics per block)
__global__ __launch_bounds__(256) void coarse_hist(const int* __restrict__ dst, int* __restrict__ ghist,
                                                   int E, int nb) {
    __shared__ int h[512];
    for (int i = threadIdx.x; i < 512; i += 256) h[i] = 0;
    __syncthreads();
    int stride = gridDim.x * 256;
    for (int e = blockIdx.x * 256 + threadIdx.x; e < E; e += stride) {
        atomicAdd(&h[dst[e] >> 8], 1);
    }
    __syncthreads();
    for (int i = threadIdx.x; i < nb; i += 256) {
        int c = h[i];
        if (c) atomicAdd(&ghist[i], c);
    }
}

// exclusive scan of nb (<=512) bucket counts; writes base[0..nb] and a working copy gcur
__global__ __launch_bounds__(64) void bucket_scan(const int* __restrict__ ghist, int* __restrict__ base,
                                                  int* __restrict__ gcur, int nb) {
    int lane = threadIdx.x;
    int carry = 0;
    for (int b0 = 0; b0 < nb; b0 += 64) {
        int i = b0 + lane;
        int v = (i < nb) ? ghist[i] : 0;
        int incl = wave_incl_scan(v, lane);
        if (i < nb) { int ex = carry + incl - v; base[i] = ex; gcur[i] = ex; }
        carry += __shfl(incl, 63);
    }
    if (lane == 0) base[nb] = carry;
}

// bin edges into coarse buckets. Per block: LDS hist of its chunk, ONE global atomic per
// (block,bucket) to reserve a contiguous run, then LDS-cursor scatter -> runs of ~10 words.
#define SCAT_CH 4096
__global__ __launch_bounds__(256) void coarse_scatter(const int* __restrict__ src, const int* __restrict__ dst,
                                                      int* __restrict__ gcur, unsigned* __restrict__ pairs,
                                                      int E, int nb) {
    __shared__ int cur[512];
    for (int i = threadIdx.x; i < 512; i += 256) cur[i] = 0;
    __syncthreads();
    int e0 = blockIdx.x * SCAT_CH;
    int e1 = min(e0 + SCAT_CH, E);
    for (int e = e0 + threadIdx.x; e < e1; e += 256) atomicAdd(&cur[dst[e] >> 8], 1);
    __syncthreads();
    for (int i = threadIdx.x; i < nb; i += 256) {
        int c = cur[i];
        cur[i] = c ? atomicAdd(&gcur[i], c) : 0;
    }
    __syncthreads();
    for (int e = e0 + threadIdx.x; e < e1; e += 256) {
        int d = dst[e];
        int r = atomicAdd(&cur[d >> 8], 1);
        pairs[r] = (unsigned)src[e] | ((unsigned)(d & 255) << 24);
    }
}

// one block per coarse bucket: fine 256-bin hist -> rowptr + dinv, then scatter colv
// entirely inside the bucket's contiguous output window (full line utilization).
__global__ __launch_bounds__(256) void fine_csr(const unsigned* __restrict__ pairs, const int* __restrict__ base,
                                                int* __restrict__ rowptr, int* __restrict__ colv,
                                                float* __restrict__ dinv, int n, int E) {
    __shared__ int h[256];
    __shared__ int cur[256];
    __shared__ int wt[4];
    int b = blockIdx.x, tid = threadIdx.x;
    int e0 = base[b], e1 = base[b + 1];
    h[tid] = 0;
    __syncthreads();
    for (int e = e0 + tid; e < e1; e += 256) atomicAdd(&h[pairs[e] >> 24], 1);
    __syncthreads();
    int v = h[tid];
    int lane = tid & 63, w = tid >> 6;
    int incl = wave_incl_scan(v, lane);
    if (lane == 63) wt[w] = incl;
    __syncthreads();
    int woff = 0;
    for (int i = 0; i < w; i++) woff += wt[i];
    int excl = woff + incl - v;
    int node = b * 256 + tid;
    if (node < n) {
        rowptr[node] = e0 + excl;
        dinv[node] = rsqrtf((float)(v + 1));  // +1 self loop
        if (node == n - 1) rowptr[n] = E;
    }
    cur[tid] = e0 + excl;
    __syncthreads();
    for (int e = e0 + tid; e < e1; e += 256) {
        unsigned p = pairs[e];
        int r = atomicAdd(&cur[p >> 24], 1);
        colv[r] = (int)(p & 0x00FFFFFFu);
    }
}

// ---------------- fused FastKAN transform (f16 MFMA, packed-f16 math) ----------------
// Block = 64 rows, 4 waves = 2 row-panels x 2 K-halves; each wave keeps 2 row-groups
// sharing each Wc B-fragment (r3) + K-split occupancy (r4) + single-pass RBF/SiLU (r6)
// + packed-f16 activation math (r7).
// Load strategy (r8/r9 A/B): NSEG==1 keeps the 2-slot prefetch ring (depth 2 = full
// depth at NCH=2; lowers liveness/VGPR). NSEG==3 uses per-chunk loads so the COMPILER
// hoists all 6 chunks' loads (explicit ring capped depth at 2: fkan3 99->113us, reverted).
// r10 lesson: do NOT fuse the gather into this kernel — gather needs one WAVE per node
// (serializing 16 nodes/wave cost 2.3x on the fused kernel).
template <int NSEG, int DOUT, int F32MASK>
__global__ __launch_bounds__(256) void fkan_kernel(
    const void* __restrict__ X0, int s0,
    const void* __restrict__ X1, int s1,
    const void* __restrict__ X2, int s2,
    const float2* __restrict__ ST0, const float2* __restrict__ ST1, const float2* __restrict__ ST2,
    const float* __restrict__ lng, const float* __restrict__ lnb,
    const ushortT* __restrict__ Wc,
    const float* __restrict__ bs, const float* __restrict__ bb,
    const float* __restrict__ dinv,
    ushortT* __restrict__ H, int hstride, int nrows) {
    constexpr int DIN = NSEG * 128;
    constexpr int KW = 5 * DIN;
    constexpr int NT = (DOUT + 15) / 16;
    constexpr int NCH = NSEG * 2;           // chunks per K-half
    constexpr bool RING = (F32MASK == 0) && (NSEG == 1);
    __shared__ float red[2][NT][4][64];  // [panel][tile][reg][lane]
    int tid = threadIdx.x;
    int w = tid >> 6, lane = tid & 63;
    int m = lane & 15, q = lane >> 4;
    int r = w & 1;    // row panel
    int kk = w >> 1;  // K half
    int baseA = blockIdx.x * 64 + r * 16;
    int baseB = baseA + 32;
    int rA = min(baseA + m, nrows - 1);
    int rB = min(baseB + m, nrows - 1);

    float muA, scA, muB, scB;
    {
        float2 st = ST0[rA]; float sum = st.x, ssq = st.y;
        if (NSEG == 3) { float2 t1 = ST1[rA]; sum += t1.x; ssq += t1.y; float2 t2 = ST2[rA]; sum += t2.x; ssq += t2.y; }
        muA = sum * (1.0f / DIN);
        float var = ssq * (1.0f / DIN) - muA * muA;
        scA = rsqrtf(fmaxf(var, 0.0f) + 1e-5f);
    }
    {
        float2 st = ST0[rB]; float sum = st.x, ssq = st.y;
        if (NSEG == 3) { float2 t1 = ST1[rB]; sum += t1.x; ssq += t1.y; float2 t2 = ST2[rB]; sum += t2.x; ssq += t2.y; }
        muB = sum * (1.0f / DIN);
        float var = ssq * (1.0f / DIN) - muB * muB;
        scB = rsqrtf(fmaxf(var, 0.0f) + 1e-5f);
    }

    float4v acc[NT][2];
    #pragma unroll
    for (int t = 0; t < NT; t++) {
        acc[t][0] = (float4v){0.f, 0.f, 0.f, 0.f};
        acc[t][1] = (float4v){0.f, 0.f, 0.f, 0.f};
    }

    // exp(-((z-G)*0.75)^2) == exp2(-(zc-Gc)^2), zc=z*CC, Gc=G*CC, CC=0.75*sqrt(log2 e)
    const float CC = 0.90084159f;
    const __half2 Gc2[4] = {
        __float2half2_rn(-2.f * CC), __float2half2_rn(-2.f / 3.f * CC),
        __float2half2_rn(2.f / 3.f * CC), __float2half2_rn(2.f * CC)};
    const __half2 NL2E = __float2half2_rn(-1.44269504f);
    const __half2 ONE2 = __float2half2_rn(1.0f);

    // ---- rolling 2-deep X prefetch ring (NSEG==1 only) ----
    uint4 rawA[2], rawB[2];
    if (RING) {
        int d00 = kk * 32 + q * 8;  // h=0: seg=0, i=kk
        rawA[0] = *(const uint4*)((const ushortT*)X0 + (size_t)rA * s0 + d00);
        rawB[0] = *(const uint4*)((const ushortT*)X0 + (size_t)rB * s0 + d00);
    }

    #pragma unroll
    for (int h = 0; h < NCH; h++) {
        const int seg = h >> 1;                 // compile-time after unroll
        int i = 2 * (h & 1) + kk;
        int d0 = i * 32 + q * 8;
        float xa[8], xb8[8];
        uint4 curA, curB;
        if (RING) {
            if (h + 1 < NCH) {                  // issue next chunk's loads EARLY
                int i2 = 2 * ((h + 1) & 1) + kk;
                int d2 = i2 * 32 + q * 8;
                rawA[(h + 1) & 1] = *(const uint4*)((const ushortT*)X0 + (size_t)rA * s0 + d2);
                rawB[(h + 1) & 1] = *(const uint4*)((const ushortT*)X0 + (size_t)rB * s0 + d2);
            }
            curA = rawA[h & 1];
            curB = rawB[h & 1];
            unpack8(curA, xa);
            unpack8(curB, xb8);
        } else {
            // per-chunk loads: fully unrolled, no ring -> compiler hoists all chunks' loads
            const void* Xp = (seg == 0) ? X0 : (seg == 1) ? X1 : X2;
            int str = (seg == 0) ? s0 : (seg == 1) ? s1 : s2;
            bool f32 = ((F32MASK >> seg) & 1) != 0;
            loadc8r(f32, Xp, (size_t)rA * str + d0, xa, curA);
            loadc8r(f32, Xp, (size_t)rB * str + d0, xb8, curB);
        }
        float4 gv0 = *(const float4*)(lng + seg * 128 + d0);
        float4 gv1 = *(const float4*)(lng + seg * 128 + d0 + 4);
        float4 bv0 = *(const float4*)(lnb + seg * 128 + d0);
        float4 bv1 = *(const float4*)(lnb + seg * 128 + d0 + 4);
        float gvs[8] = {gv0.x, gv0.y, gv0.z, gv0.w, gv1.x, gv1.y, gv1.z, gv1.w};
        float bvs[8] = {bv0.x, bv0.y, bv0.z, bv0.w, bv1.x, bv1.y, bv1.z, bv1.w};
        float za[8], zb[8];
        #pragma unroll
        for (int j = 0; j < 8; j++) {
            za[j] = (xa[j] - muA) * scA * gvs[j] + bvs[j];
            zb[j] = (xb8[j] - muB) * scB * gvs[j] + bvs[j];
        }
        // pack zc = z*CC
        __half2 zhA[4], zhB[4];
        #pragma unroll
        for (int p = 0; p < 4; p++) {
            zhA[p] = __builtin_bit_cast(__half2, pkrtz(za[2 * p] * CC, za[2 * p + 1] * CC));
            zhB[p] = __builtin_bit_cast(__half2, pkrtz(zb[2 * p] * CC, zb[2 * p + 1] * CC));
        }
        // RBF: 4 grid points, packed f16; exp output IS the fragment pair
        #pragma unroll
        for (int g = 0; g < 4; g++) {
            uint4v ua, ub;
            #pragma unroll
            for (int p = 0; p < 4; p++) {
                __half2 dA = __hsub2(zhA[p], Gc2[g]);
                ua[p] = __builtin_bit_cast(unsigned, h2exp2(__hmul2(dA, __hneg2(dA))));
                __half2 dB = __hsub2(zhB[p], Gc2[g]);
                ub[p] = __builtin_bit_cast(unsigned, h2exp2(__hmul2(dB, __hneg2(dB))));
            }
            f16x8 afa = __builtin_bit_cast(f16x8, ua);
            f16x8 afb = __builtin_bit_cast(f16x8, ub);
            int kbase = seg * 512 + g * 128 + i * 32;
            #pragma unroll
            for (int t = 0; t < NT; t++) {
                int n = t * 16 + m;
                f16x8 bfr = (f16x8)(_Float16)0;
                if ((DOUT % 16 == 0) || (n < DOUT))
                    bfr = *(const f16x8*)(Wc + (size_t)n * KW + kbase + q * 8);
                acc[t][0] = __builtin_amdgcn_mfma_f32_16x16x32_f16(afa, bfr, acc[t][0], 0, 0, 0);
                acc[t][1] = __builtin_amdgcn_mfma_f32_16x16x32_f16(afb, bfr, acc[t][1], 0, 0, 0);
            }
        }
        // SiLU from raw f16 pairs: x * 1/(1 + exp2(-x*log2e))
        {
            unsigned raA[4] = {curA.x, curA.y, curA.z, curA.w};
            unsigned raB[4] = {curB.x, curB.y, curB.z, curB.w};
            uint4v ua, ub;
            #pragma unroll
            for (int p = 0; p < 4; p++) {
                __half2 xhA = __builtin_bit_cast(__half2, raA[p]);
                __half2 sgA = h2rcp(__hadd2(ONE2, h2exp2(__hmul2(xhA, NL2E))));
                ua[p] = __builtin_bit_cast(unsigned, __hmul2(xhA, sgA));
                __half2 xhB = __builtin_bit_cast(__half2, raB[p]);
                __half2 sgB = h2rcp(__hadd2(ONE2, h2exp2(__hmul2(xhB, NL2E))));
                ub[p] = __builtin_bit_cast(unsigned, __hmul2(xhB, sgB));
            }
            f16x8 afa = __builtin_bit_cast(f16x8, ua);
            f16x8 afb = __builtin_bit_cast(f16x8, ub);
            int kbase = 4 * DIN + seg * 128 + i * 32;
            #pragma unroll
            for (int t = 0; t < NT; t++) {
                int n = t * 16 + m;
                f16x8 bfr = (f16x8)(_Float16)0;
                if ((DOUT % 16 == 0) || (n < DOUT))
                    bfr = *(const f16x8*)(Wc + (size_t)n * KW + kbase + q * 8);
                acc[t][0] = __builtin_amdgcn_mfma_f32_16x16x32_f16(afa, bfr, acc[t][0], 0, 0, 0);
                acc[t][1] = __builtin_amdgcn_mfma_f32_16x16x32_f16(afb, bfr, acc[t][1], 0, 0, 0);
            }
        }
    }

    // ---- cross-wave K-half reduction (2 barriers, self-ordered LDS reuse) ----
    if (kk == 1) {
        #pragma unroll
        for (int t = 0; t < NT; t++)
            #pragma unroll
            for (int j = 0; j < 4; j++) red[r][t][j][lane] = acc[t][0][j];
    }
    __syncthreads();
    if (kk == 0) {
        #pragma unroll
        for (int t = 0; t < NT; t++)
            #pragma unroll
            for (int j = 0; j < 4; j++) {
                acc[t][0][j] += red[r][t][j][lane];  // full group-A sum
                red[r][t][j][lane] = acc[t][1][j];   // hand B partial to the k=1 wave
            }
    }
    __syncthreads();
    if (kk == 1) {
        #pragma unroll
        for (int t = 0; t < NT; t++)
            #pragma unroll
            for (int j = 0; j < 4; j++) acc[t][1][j] += red[r][t][j][lane];  // full group-B sum
    }

    // ---- epilogue: kk=0 stores group A, kk=1 stores group B (C/D: col=lane&15, row=q*4+j) ----
    int gbase = (kk == 0) ? baseA : baseB;
    float dd[4];
    #pragma unroll
    for (int j = 0; j < 4; j++) {
        int row = gbase + q * 4 + j;
        dd[j] = (row < nrows) ? dinv[row] : 0.f;
    }
    if (kk == 0) {
        #pragma unroll
        for (int t = 0; t < NT; t++) {
            int col = t * 16 + m;
            if ((DOUT % 16 == 0) || (col < DOUT)) {
                float bias = bs[col] + bb[col];
                #pragma unroll
                for (int j = 0; j < 4; j++) {
                    int row = gbase + q * 4 + j;
                    if (row < nrows) H[(size_t)row * hstride + col] = f2h((acc[t][0][j] + bias) * dd[j]);
                }
            }
        }
    } else {
        #pragma unroll
        for (int t = 0; t < NT; t++) {
            int col = t * 16 + m;
            if ((DOUT % 16 == 0) || (col < DOUT)) {
                float bias = bs[col] + bb[col];
                #pragma unroll
                for (int j = 0; j < 4; j++) {
                    int row = gbase + q * 4 + j;
                    if (row < nrows) H[(size_t)row * hstride + col] = f2h((acc[t][1][j] + bias) * dd[j]);
                }
            }
        }
    }
}

// ---------------- aggregation: wave per node, 32 load-streams in flight ----------------
// H (f16) is pre-scaled by dinv[src]. out = dinv[wid]*(H[wid] + sum_nbr H[s]) + bg.
// Round-11: 8 edge-groups x 8 lanes, 2 contiguous uint4/lane, 2-deep -> 32 outstanding
// 16B loads/wave (was 8). Same bytes; probes whether agg is MLP-bound vs L3-BW-bound.

__global__ __launch_bounds__(256) void agg128_kernel(
    const ushortT* __restrict__ H, ushortT* __restrict__ OUT,
    const float* __restrict__ bg, const int* __restrict__ rowptr,
    const int* __restrict__ colv, const float* __restrict__ dinv,
    float2* __restrict__ STout, int n) {
    int wid = (blockIdx.x * 256 + threadIdx.x) >> 6;
    int lane = threadIdx.x & 63;
    if (wid >= n) return;
    int g = lane >> 3, t = lane & 7;   // 8 groups x 8 lanes; lane covers cols t*16..t*16+15
    float di = dinv[wid];
    float a[16] = {0.f, 0.f, 0.f, 0.f, 0.f, 0.f, 0.f, 0.f,
                   0.f, 0.f, 0.f, 0.f, 0.f, 0.f, 0.f, 0.f};
    if (g == 0) {  // self
        const ushortT* rs = H + (size_t)wid * 128 + t * 16;
        unpack_add(*(const uint4*)rs, a);
        unpack_add(*(const uint4*)(rs + 8), a + 8);
    }
    int e0 = rowptr[wid], e1 = rowptr[wid + 1];
    int e = e0 + g;
    for (; e + 8 < e1; e += 16) {
        int s0i = colv[e], s1i = colv[e + 8];
        const ushortT* r0 = H + (size_t)s0i * 128 + t * 16;
        const ushortT* r1 = H + (size_t)s1i * 128 + t * 16;
        uint4 v00 = *(const uint4*)r0;
        uint4 v01 = *(const uint4*)(r0 + 8);
        uint4 v10 = *(const uint4*)r1;
        uint4 v11 = *(const uint4*)(r1 + 8);
        unpack_add(v00, a);
        unpack_add(v01, a + 8);
        unpack_add(v10, a);
        unpack_add(v11, a + 8);
    }
    if (e < e1) {  // stride-8 walker: at most one edge left after main loop
        const ushortT* r0 = H + (size_t)colv[e] * 128 + t * 16;
        unpack_add(*(const uint4*)r0, a);
        unpack_add(*(const uint4*)(r0 + 8), a + 8);
    }
    #pragma unroll
    for (int j = 0; j < 16; j++) {
        a[j] += __shfl_xor(a[j], 8);
        a[j] += __shfl_xor(a[j], 16);
        a[j] += __shfl_xor(a[j], 32);
    }
    if (g == 0) {
        float4 b0 = *(const float4*)(bg + t * 16);
        float4 b1 = *(const float4*)(bg + t * 16 + 4);
        float4 b2 = *(const float4*)(bg + t * 16 + 8);
        float4 b3 = *(const float4*)(bg + t * 16 + 12);
        float bgs[16] = {b0.x, b0.y, b0.z, b0.w, b1.x, b1.y, b1.z, b1.w,
                         b2.x, b2.y, b2.z, b2.w, b3.x, b3.y, b3.z, b3.w};
        unsigned rb[16];
        float s = 0.f, ss = 0.f;
        #pragma unroll
        for (int j = 0; j < 16; j++) {
            float o = di * a[j] + bgs[j];
            rb[j] = f2h(o);                       // RTNE; stored value
            float back = h2f((unsigned short)rb[j]);
            s += back; ss += back * back;         // stats of STORED values (LN consistency)
        }
        uint4 pk0, pk1;
        pk0.x = rb[0] | (rb[1] << 16);
        pk0.y = rb[2] | (rb[3] << 16);
        pk0.z = rb[4] | (rb[5] << 16);
        pk0.w = rb[6] | (rb[7] << 16);
        pk1.x = rb[8] | (rb[9] << 16);
        pk1.y = rb[10] | (rb[11] << 16);
        pk1.z = rb[12] | (rb[13] << 16);
        pk1.w = rb[14] | (rb[15] << 16);
        ushortT* po = OUT + (size_t)wid * 128 + t * 16;
        *(uint4*)po = pk0;
        *(uint4*)(po + 8) = pk1;
        #pragma unroll
        for (int d = 1; d < 8; d <<= 1) { s += __shfl_xor(s, d); ss += __shfl_xor(ss, d); }
        if (t == 0) STout[wid] = make_float2(s, ss);
    }
}

// H stride 64 (cols 47..63 junk, never written out). 16 edge-streams in flight.
__global__ __launch_bounds__(256) void agg47_kernel(
    const ushortT* __restrict__ H, float* __restrict__ OUT,
    const float* __restrict__ bg, const int* __restrict__ rowptr,
    const int* __restrict__ colv, const float* __restrict__ dinv, int n) {
    int wid = (blockIdx.x * 256 + threadIdx.x) >> 6;
    int lane = threadIdx.x & 63;
    if (wid >= n) return;
    int g = lane >> 3, t = lane & 7;
    float di = dinv[wid];
    float a[8] = {0.f, 0.f, 0.f, 0.f, 0.f, 0.f, 0.f, 0.f};
    if (g == 0) unpack_add(*(const uint4*)(H + (size_t)wid * 64 + t * 8), a);  // self
    int e0 = rowptr[wid], e1 = rowptr[wid + 1];
    int e = e0 + g;
    for (; e + 8 < e1; e += 16) {
        int s0i = colv[e], s1i = colv[e + 8];
        uint4 v0 = *(const uint4*)(H + (size_t)s0i * 64 + t * 8);
        uint4 v1 = *(const uint4*)(H + (size_t)s1i * 64 + t * 8);
        unpack_add(v0, a);
        unpack_add(v1, a);
    }
    if (e < e1) {
        unpack_add(*(const uint4*)(H + (size_t)colv[e] * 64 + t * 8), a);
    }
    #pragma unroll
    for (int j = 0; j < 8; j++) {
        a[j] += __shfl_xor(a[j], 8);
        a[j] += __shfl_xor(a[j], 16);
        a[j] += __shfl_xor(a[j], 32);
    }
    if (g == 0) {
        #pragma unroll
        for (int j = 0; j < 8; j++) {
            int c = t * 8 + j;
            if (c < 47) OUT[(size_t)wid * 47 + c] = di * a[j] + bg[c];
        }
    }
}

// ---------------- launcher ----------------

extern "C" void kernel_launch(void* const* d_in, const int* in_sizes, int n_in,
                              void* d_out, int out_size, void* d_ws, size_t ws_size,
                              hipStream_t stream) {
    const float* x = (const float*)d_in[0];
    const int* ei = (const int*)d_in[1];
    const float* lng0 = (const float*)d_in[2];
    const float* lnb0 = (const float*)d_in[3];
    const float* Ws0 = (const float*)d_in[4];
    const float* bs0 = (const float*)d_in[5];
    const float* Wb0 = (const float*)d_in[6];
    const float* bb0 = (const float*)d_in[7];
    const float* bg0 = (const float*)d_in[8];
    const float* lng1 = (const float*)d_in[9];
    const float* lnb1 = (const float*)d_in[10];
    const float* Ws1 = (const float*)d_in[11];
    const float* bs1 = (const float*)d_in[12];
    const float* Wb1 = (const float*)d_in[13];
    const float* bb1 = (const float*)d_in[14];
    const float* bg1 = (const float*)d_in[15];
    const float* lng2 = (const float*)d_in[16];
    const float* lnb2 = (const float*)d_in[17];
    const float* Ws2 = (const float*)d_in[18];
    const float* bs2 = (const float*)d_in[19];
    const float* Wb2 = (const float*)d_in[20];
    const float* bb2 = (const float*)d_in[21];
    const float* bg2 = (const float*)d_in[22];

    const int N = in_sizes[0] / 128;
    const int E = in_sizes[1] / 2;
    const int NB = (N + 255) >> 8;  // coarse buckets of 256 nodes (requires N < 2^24)

    char* wsp = (char*)d_ws;
    size_t off = 0;
    auto alloc = [&](size_t bytes) {
        off = (off + 255) & ~(size_t)255;
        void* p = wsp + off;
        off += bytes;
        return p;
    };
    int* ghist = (int*)alloc(512 * 4);
    int* bbase = (int*)alloc(513 * 4);
    int* gcur = (int*)alloc(512 * 4);
    int* rowptr = (int*)alloc((size_t)(N + 1) * 4);
    int* colv = (int*)alloc((size_t)E * 4);
    float* dinvv = (float*)alloc((size_t)N * 4);
    ushortT* hbuf = (ushortT*)alloc((size_t)N * 128 * 2);
    ushortT* a1 = (ushortT*)alloc((size_t)N * 128 * 2);
    ushortT* a2 = (ushortT*)alloc((size_t)N * 128 * 2);
    float2* stx = (float2*)alloc((size_t)N * 8);
    float2* st1 = (float2*)alloc((size_t)N * 8);
    float2* st2 = (float2*)alloc((size_t)N * 8);
    ushortT* Wc0 = (ushortT*)alloc((size_t)128 * 640 * 2);
    ushortT* Wc1 = (ushortT*)alloc((size_t)128 * 640 * 2);
    ushortT* Wc2 = (ushortT*)alloc((size_t)47 * 1920 * 2);
    size_t off_base = off;
    ushortT* xb = (ushortT*)alloc((size_t)N * 128 * 2);  // f16 mirror of x
    bool fits = (off <= ws_size);
    if (!fits) off = off_base;
    (void)n_in; (void)out_size;

    // pairs staging aliases hbuf: pairs is dead before the first fkan writes hbuf.
    unsigned* pairs = (unsigned*)hbuf;

    const int* srcp = ei;
    const int* dstp = ei + E;

    int gF = (N + 63) / 64;
    int gW = (N + 3) / 4;
    int gScat = (E + SCAT_CH - 1) / SCAT_CH;

    // single launch: all three Wc builds + ghist zeroing (993 + 2 blocks)
    build_wc3<<<995, 256, 0, stream>>>(Ws0, Wb0, Wc0, Ws1, Wb1, Wc1, Ws2, Wb2, Wc2, ghist);

    // CSR build: coarse hist -> scan -> coarse scatter (packed pairs) -> fine per-bucket CSR
    coarse_hist<<<NB, 256, 0, stream>>>(dstp, ghist, E, NB);
    bucket_scan<<<1, 64, 0, stream>>>(ghist, bbase, gcur, NB);
    coarse_scatter<<<gScat, 256, 0, stream>>>(srcp, dstp, gcur, pairs, E, NB);
    fine_csr<<<NB, 256, 0, stream>>>(pairs, bbase, rowptr, colv, dinvv, N, E);

    stats_f32<<<gW, 256, 0, stream>>>(x, stx, fits ? xb : nullptr, N);

    // layer 1
    if (fits)
        fkan_kernel<1, 128, 0><<<gF, 256, 0, stream>>>(xb, 128, xb, 128, xb, 128, stx, stx, stx,
                                                       lng0, lnb0, Wc0, bs0, bb0, dinvv, hbuf, 128, N);
    else
        fkan_kernel<1, 128, 1><<<gF, 256, 0, stream>>>(x, 128, x, 128, x, 128, stx, stx, stx,
                                                       lng0, lnb0, Wc0, bs0, bb0, dinvv, hbuf, 128, N);
    agg128_kernel<<<gW, 256, 0, stream>>>(hbuf, a1, bg0, rowptr, colv, dinvv, st1, N);

    // layer 2
    fkan_kernel<1, 128, 0><<<gF, 256, 0, stream>>>(a1, 128, a1, 128, a1, 128, st1, st1, st1,
                                                   lng1, lnb1, Wc1, bs1, bb1, dinvv, hbuf, 128, N);
    agg128_kernel<<<gW, 256, 0, stream>>>(hbuf, a2, bg1, rowptr, colv, dinvv, st2, N);

    // layer 3 (hbuf stride 64)
    if (fits)
        fkan_kernel<3, 47, 0><<<gF, 256, 0, stream>>>(xb, 128, a1, 128, a2, 128, stx, st1, st2,
                                                      lng2, lnb2, Wc2, bs2, bb2, dinvv, hbuf, 64, N);
    else
        fkan_kernel<3, 47, 1><<<gF, 256, 0, stream>>>(x, 128, a1, 128, a2, 128, stx, st1, st2,
                                                      lng2, lnb2, Wc2, bs2, bb2, dinvv, hbuf, 64, N);
    agg47_kernel<<<gW, 256, 0, stream>>>(hbuf, (float*)d_out, bg2, rowptr, colv, dinvv, N);
}

// Round 12
// 670.445 us; speedup vs baseline: 1.2286x; 1.0398x over previous
//
#include <hip/hip_runtime.h>
#include <hip/hip_fp16.h>

typedef unsigned short ushortT;
typedef _Float16 f16x8 __attribute__((ext_vector_type(8)));
typedef __attribute__((ext_vector_type(4))) float float4v;
typedef __attribute__((ext_vector_type(4))) unsigned int uint4v;

__device__ __forceinline__ unsigned short f2h(float f) {  // RTNE f32->f16 (v_cvt_f16_f32)
    _Float16 h = (_Float16)f;
    return __builtin_bit_cast(unsigned short, h);
}
__device__ __forceinline__ float h2f(unsigned short b) {  // v_cvt_f32_f16
    return (float)__builtin_bit_cast(_Float16, b);
}
// packed f32x2 -> f16x2, RTZ (v_cvt_pkrtz_f16_f32, 1 inst).
__device__ __forceinline__ unsigned pkrtz(float lo, float hi) {
    auto h = __builtin_amdgcn_cvt_pkrtz(lo, hi);
    return __builtin_bit_cast(unsigned, h);
}
__device__ __forceinline__ void unpack8(uint4 v, float o[8]) {
    unsigned uu[4] = {v.x, v.y, v.z, v.w};
    #pragma unroll
    for (int j = 0; j < 8; j++) o[j] = h2f((unsigned short)(uu[j >> 1] >> ((j & 1) * 16)));
}
__device__ __forceinline__ void unpack_fma(uint4 v, float sc, float a[8]) {  // a += sc*h
    unsigned uu[4] = {v.x, v.y, v.z, v.w};
    #pragma unroll
    for (int j = 0; j < 8; j++) a[j] += sc * h2f((unsigned short)(uu[j >> 1] >> ((j & 1) * 16)));
}

// 8-element row load (f32 fallback path); also returns raw f16 pairs
__device__ __forceinline__ void loadc8r(bool f32, const void* p, size_t off, float o[8], uint4& raw) {
    if (f32) {
        const float* q = (const float*)p + off;
        float4 a = *(const float4*)q;
        float4 b = *(const float4*)(q + 4);
        o[0] = a.x; o[1] = a.y; o[2] = a.z; o[3] = a.w;
        o[4] = b.x; o[5] = b.y; o[6] = b.z; o[7] = b.w;
        raw.x = pkrtz(a.x, a.y); raw.y = pkrtz(a.z, a.w);
        raw.z = pkrtz(b.x, b.y); raw.w = pkrtz(b.z, b.w);
    } else {
        uint4 v = *(const uint4*)((const ushortT*)p + off);
        raw = v;
        unpack8(v, o);
    }
}

// ---------------- fused setup launch: Wc builds + ghist zero + LN stats ----------------
// Grid: [0,320) Wc0, [320,640) Wc1, [640,993) Wc2, [993,995) zero ghist, [995,995+gW) stats.
__global__ __launch_bounds__(256) void build_wc3s(
    const float* __restrict__ Ws0, const float* __restrict__ Wb0, ushortT* __restrict__ Wc0,
    const float* __restrict__ Ws1, const float* __restrict__ Wb1, ushortT* __restrict__ Wc1,
    const float* __restrict__ Ws2, const float* __restrict__ Wb2, ushortT* __restrict__ Wc2,
    int* __restrict__ ghist,
    const float* __restrict__ X, float2* __restrict__ ST, ushortT* __restrict__ xb, int n) {
    int b = blockIdx.x;
    if (b >= 995) {  // per-row LN stats for f32 x (+ optional f16 mirror)
        int wid = ((b - 995) * 256 + threadIdx.x) >> 6;
        int lane = threadIdx.x & 63;
        if (wid >= n) return;
        float2 v = *(const float2*)(X + (size_t)wid * 128 + lane * 2);
        if (xb) {
            *(unsigned*)(xb + (size_t)wid * 128 + lane * 2) = pkrtz(v.x, v.y);
        }
        float s = v.x + v.y, ss = v.x * v.x + v.y * v.y;
        #pragma unroll
        for (int d = 1; d < 64; d <<= 1) { s += __shfl_xor(s, d); ss += __shfl_xor(ss, d); }
        if (lane == 0) ST[wid] = make_float2(s, ss);
        return;
    }
    if (b >= 993) {
        int i = (b - 993) * 256 + threadIdx.x;
        if (i < 512) ghist[i] = 0;
        return;
    }
    const float *Ws, *Wb;
    ushortT* Wc;
    int dout, din, base;
    if (b < 320) { Ws = Ws0; Wb = Wb0; Wc = Wc0; dout = 128; din = 128; base = b; }
    else if (b < 640) { Ws = Ws1; Wb = Wb1; Wc = Wc1; dout = 128; din = 128; base = b - 320; }
    else { Ws = Ws2; Wb = Wb2; Wc = Wc2; dout = 47; din = 384; base = b - 640; }
    int idx = base * 256 + threadIdx.x;
    int kw = 5 * din;
    if (idx >= dout * kw) return;
    int nn = idx / kw, c = idx % kw;
    float v;
    if (c < 4 * din) {
        int seg = c >> 9;
        int rem = c & 511;
        int g = rem >> 7;
        int dl = rem & 127;
        v = Ws[(size_t)nn * 4 * din + 4 * (seg * 128 + dl) + g];
    } else {
        v = Wb[(size_t)nn * din + (c - 4 * din)];
    }
    Wc[idx] = f2h(v);
}

// ---------------- CSR build: two-level counting sort ----------------
// Pack: src (bits 0..23, N < 2^24) | (dst & 255) << 24. Coarse bucket = dst >> 8.

__device__ __forceinline__ int wave_incl_scan(int v, int lane) {
    #pragma unroll
    for (int d = 1; d < 64; d <<= 1) {
        int o = __shfl_up(v, d);
        if (lane >= d) v += o;
    }
    return v;
}

__global__ __launch_bounds__(256) void coarse_hist(const int* __restrict__ dst, int* __restrict__ ghist,
                                                   int E, int nb) {
    __shared__ int h[512];
    for (int i = threadIdx.x; i < 512; i += 256) h[i] = 0;
    __syncthreads();
    int stride = gridDim.x * 256;
    for (int e = blockIdx.x * 256 + threadIdx.x; e < E; e += stride) {
        atomicAdd(&h[dst[e] >> 8], 1);
    }
    __syncthreads();
    for (int i = threadIdx.x; i < nb; i += 256) {
        int c = h[i];
        if (c) atomicAdd(&ghist[i], c);
    }
}

__global__ __launch_bounds__(64) void bucket_scan(const int* __restrict__ ghist, int* __restrict__ base,
                                                  int* __restrict__ gcur, int nb) {
    int lane = threadIdx.x;
    int carry = 0;
    for (int b0 = 0; b0 < nb; b0 += 64) {
        int i = b0 + lane;
        int v = (i < nb) ? ghist[i] : 0;
        int incl = wave_incl_scan(v, lane);
        if (i < nb) { int ex = carry + incl - v; base[i] = ex; gcur[i] = ex; }
        carry += __shfl(incl, 63);
    }
    if (lane == 0) base[nb] = carry;
}

#define SCAT_CH 4096
__global__ __launch_bounds__(256) void coarse_scatter(const int* __restrict__ src, const int* __restrict__ dst,
                                                      int* __restrict__ gcur, unsigned* __restrict__ pairs,
                                                      int E, int nb) {
    __shared__ int cur[512];
    for (int i = threadIdx.x; i < 512; i += 256) cur[i] = 0;
    __syncthreads();
    int e0 = blockIdx.x * SCAT_CH;
    int e1 = min(e0 + SCAT_CH, E);
    for (int e = e0 + threadIdx.x; e < e1; e += 256) atomicAdd(&cur[dst[e] >> 8], 1);
    __syncthreads();
    for (int i = threadIdx.x; i < nb; i += 256) {
        int c = cur[i];
        cur[i] = c ? atomicAdd(&gcur[i], c) : 0;
    }
    __syncthreads();
    for (int e = e0 + threadIdx.x; e < e1; e += 256) {
        int d = dst[e];
        int r = atomicAdd(&cur[d >> 8], 1);
        pairs[r] = (unsigned)src[e] | ((unsigned)(d & 255) << 24);
    }
}

// ---------------- fused fine_csr + layer-1 fkan (grid-partitioned) ----------------
// Blocks [0,nb): per-bucket fine CSR (rowptr/colv/dinv). Blocks [nb,nb+gF): fkan layer 1.
// Legal because fkan no longer reads rowptr/colv/dinv (dinv moved into agg gather) —
// the latency/atomic-bound CSR work overlaps the MFMA-bound transform (r10 lesson kept:
// the gather itself stays one-wave-per-node in agg128).
template <int F32MASK>
__global__ __launch_bounds__(256) void csr_fkan1(
    const unsigned* __restrict__ pairs, const int* __restrict__ bbase,
    int* __restrict__ rowptr, int* __restrict__ colv, float* __restrict__ dinv,
    int nb, int E,
    const void* __restrict__ X0, int s0,
    const float2* __restrict__ ST0,
    const float* __restrict__ lng, const float* __restrict__ lnb,
    const ushortT* __restrict__ Wc,
    const float* __restrict__ bs, const float* __restrict__ bb,
    ushortT* __restrict__ H, int nrows) {
    constexpr int NT = 8;                 // DOUT=128
    constexpr bool RING = (F32MASK == 0);
    __shared__ __align__(16) char smem[16384];  // union: csr{h,cur,wt} | fkan red
    int tid = threadIdx.x;

    if ((int)blockIdx.x < nb) {
        // ---- fine CSR: 256-bin hist -> rowptr+dinv, scatter colv in-bucket ----
        int* h = (int*)smem;
        int* cur = h + 256;
        int* wt = cur + 256;
        int b = blockIdx.x;
        int e0 = bbase[b], e1 = bbase[b + 1];
        h[tid] = 0;
        __syncthreads();
        for (int e = e0 + tid; e < e1; e += 256) atomicAdd(&h[pairs[e] >> 24], 1);
        __syncthreads();
        int v = h[tid];
        int lane = tid & 63, w = tid >> 6;
        int incl = wave_incl_scan(v, lane);
        if (lane == 63) wt[w] = incl;
        __syncthreads();
        int woff = 0;
        for (int i = 0; i < w; i++) woff += wt[i];
        int excl = woff + incl - v;
        int node = b * 256 + tid;
        if (node < nrows) {
            rowptr[node] = e0 + excl;
            dinv[node] = rsqrtf((float)(v + 1));  // +1 self loop
            if (node == nrows - 1) rowptr[nrows] = E;
        }
        cur[tid] = e0 + excl;
        __syncthreads();
        for (int e = e0 + tid; e < e1; e += 256) {
            unsigned p = pairs[e];
            int r = atomicAdd(&cur[p >> 24], 1);
            colv[r] = (int)(p & 0x00FFFFFFu);
        }
        return;
    }

    // ---- fkan layer 1 (NSEG=1, DOUT=128; r9 body, no dinv in epilogue) ----
    int bid = blockIdx.x - nb;
    float* red = (float*)smem;  // [2][NT][4][64] f32
    int w = tid >> 6, lane = tid & 63;
    int m = lane & 15, q = lane >> 4;
    int r = w & 1;    // row panel
    int kk = w >> 1;  // K half
    int baseA = bid * 64 + r * 16;
    int baseB = baseA + 32;
    int rA = min(baseA + m, nrows - 1);
    int rB = min(baseB + m, nrows - 1);

    float muA, scA, muB, scB;
    {
        float2 st = ST0[rA];
        muA = st.x * (1.0f / 128.0f);
        float var = st.y * (1.0f / 128.0f) - muA * muA;
        scA = rsqrtf(fmaxf(var, 0.0f) + 1e-5f);
    }
    {
        float2 st = ST0[rB];
        muB = st.x * (1.0f / 128.0f);
        float var = st.y * (1.0f / 128.0f) - muB * muB;
        scB = rsqrtf(fmaxf(var, 0.0f) + 1e-5f);
    }

    float4v acc[NT][2];
    #pragma unroll
    for (int t = 0; t < NT; t++) {
        acc[t][0] = (float4v){0.f, 0.f, 0.f, 0.f};
        acc[t][1] = (float4v){0.f, 0.f, 0.f, 0.f};
    }

    const float CC = 0.90084159f;  // 0.75*sqrt(log2 e)
    const __half2 Gc2[4] = {
        __float2half2_rn(-2.f * CC), __float2half2_rn(-2.f / 3.f * CC),
        __float2half2_rn(2.f / 3.f * CC), __float2half2_rn(2.f * CC)};
    const __half2 NL2E = __float2half2_rn(-1.44269504f);
    const __half2 ONE2 = __float2half2_rn(1.0f);

    uint4 rawA[2], rawB[2];
    if (RING) {
        int d00 = kk * 32 + q * 8;
        rawA[0] = *(const uint4*)((const ushortT*)X0 + (size_t)rA * s0 + d00);
        rawB[0] = *(const uint4*)((const ushortT*)X0 + (size_t)rB * s0 + d00);
    }

    #pragma unroll
    for (int h = 0; h < 2; h++) {
        int i = 2 * h + kk;
        int d0 = i * 32 + q * 8;
        float xa[8], xb8[8];
        uint4 curA, curB;
        if (RING) {
            if (h == 0) {
                int i2 = 2 + kk;
                int d2 = i2 * 32 + q * 8;
                rawA[1] = *(const uint4*)((const ushortT*)X0 + (size_t)rA * s0 + d2);
                rawB[1] = *(const uint4*)((const ushortT*)X0 + (size_t)rB * s0 + d2);
            }
            curA = rawA[h];
            curB = rawB[h];
            unpack8(curA, xa);
            unpack8(curB, xb8);
        } else {
            loadc8r(true, X0, (size_t)rA * s0 + d0, xa, curA);
            loadc8r(true, X0, (size_t)rB * s0 + d0, xb8, curB);
        }
        float4 gv0 = *(const float4*)(lng + d0);
        float4 gv1 = *(const float4*)(lng + d0 + 4);
        float4 bv0 = *(const float4*)(lnb + d0);
        float4 bv1 = *(const float4*)(lnb + d0 + 4);
        float gvs[8] = {gv0.x, gv0.y, gv0.z, gv0.w, gv1.x, gv1.y, gv1.z, gv1.w};
        float bvs[8] = {bv0.x, bv0.y, bv0.z, bv0.w, bv1.x, bv1.y, bv1.z, bv1.w};
        float za[8], zb[8];
        #pragma unroll
        for (int j = 0; j < 8; j++) {
            za[j] = (xa[j] - muA) * scA * gvs[j] + bvs[j];
            zb[j] = (xb8[j] - muB) * scB * gvs[j] + bvs[j];
        }
        __half2 zhA[4], zhB[4];
        #pragma unroll
        for (int p = 0; p < 4; p++) {
            zhA[p] = __builtin_bit_cast(__half2, pkrtz(za[2 * p] * CC, za[2 * p + 1] * CC));
            zhB[p] = __builtin_bit_cast(__half2, pkrtz(zb[2 * p] * CC, zb[2 * p + 1] * CC));
        }
        #pragma unroll
        for (int g = 0; g < 4; g++) {
            uint4v ua, ub;
            #pragma unroll
            for (int p = 0; p < 4; p++) {
                __half2 dA = __hsub2(zhA[p], Gc2[g]);
                ua[p] = __builtin_bit_cast(unsigned, h2exp2(__hmul2(dA, __hneg2(dA))));
                __half2 dB = __hsub2(zhB[p], Gc2[g]);
                ub[p] = __builtin_bit_cast(unsigned, h2exp2(__hmul2(dB, __hneg2(dB))));
            }
            f16x8 afa = __builtin_bit_cast(f16x8, ua);
            f16x8 afb = __builtin_bit_cast(f16x8, ub);
            int kbase = g * 128 + i * 32;
            #pragma unroll
            for (int t = 0; t < NT; t++) {
                int n = t * 16 + m;
                f16x8 bfr = *(const f16x8*)(Wc + (size_t)n * 640 + kbase + q * 8);
                acc[t][0] = __builtin_amdgcn_mfma_f32_16x16x32_f16(afa, bfr, acc[t][0], 0, 0, 0);
                acc[t][1] = __builtin_amdgcn_mfma_f32_16x16x32_f16(afb, bfr, acc[t][1], 0, 0, 0);
            }
        }
        {
            unsigned raA[4] = {curA.x, curA.y, curA.z, curA.w};
            unsigned raB[4] = {curB.x, curB.y, curB.z, curB.w};
            uint4v ua, ub;
            #pragma unroll
            for (int p = 0; p < 4; p++) {
                __half2 xhA = __builtin_bit_cast(__half2, raA[p]);
                __half2 sgA = h2rcp(__hadd2(ONE2, h2exp2(__hmul2(xhA, NL2E))));
                ua[p] = __builtin_bit_cast(unsigned, __hmul2(xhA, sgA));
                __half2 xhB = __builtin_bit_cast(__half2, raB[p]);
                __half2 sgB = h2rcp(__hadd2(ONE2, h2exp2(__hmul2(xhB, NL2E))));
                ub[p] = __builtin_bit_cast(unsigned, __hmul2(xhB, sgB));
            }
            f16x8 afa = __builtin_bit_cast(f16x8, ua);
            f16x8 afb = __builtin_bit_cast(f16x8, ub);
            int kbase = 512 + i * 32;
            #pragma unroll
            for (int t = 0; t < NT; t++) {
                int n = t * 16 + m;
                f16x8 bfr = *(const f16x8*)(Wc + (size_t)n * 640 + kbase + q * 8);
                acc[t][0] = __builtin_amdgcn_mfma_f32_16x16x32_f16(afa, bfr, acc[t][0], 0, 0, 0);
                acc[t][1] = __builtin_amdgcn_mfma_f32_16x16x32_f16(afb, bfr, acc[t][1], 0, 0, 0);
            }
        }
    }

    if (kk == 1) {
        #pragma unroll
        for (int t = 0; t < NT; t++)
            #pragma unroll
            for (int j = 0; j < 4; j++) red[((r * NT + t) * 4 + j) * 64 + lane] = acc[t][0][j];
    }
    __syncthreads();
    if (kk == 0) {
        #pragma unroll
        for (int t = 0; t < NT; t++)
            #pragma unroll
            for (int j = 0; j < 4; j++) {
                acc[t][0][j] += red[((r * NT + t) * 4 + j) * 64 + lane];
                red[((r * NT + t) * 4 + j) * 64 + lane] = acc[t][1][j];
            }
    }
    __syncthreads();
    if (kk == 1) {
        #pragma unroll
        for (int t = 0; t < NT; t++)
            #pragma unroll
            for (int j = 0; j < 4; j++) acc[t][1][j] += red[((r * NT + t) * 4 + j) * 64 + lane];
    }

    int gbase = (kk == 0) ? baseA : baseB;
    int side = (kk == 0) ? 0 : 1;
    #pragma unroll
    for (int t = 0; t < NT; t++) {
        int col = t * 16 + m;
        float bias = bs[col] + bb[col];
        #pragma unroll
        for (int j = 0; j < 4; j++) {
            int row = gbase + q * 4 + j;
            if (row < nrows) H[(size_t)row * 128 + col] = f2h(acc[t][side][j] + bias);
        }
    }
}

// ---------------- fused FastKAN transform, layers 2/3 (no dinv; raw h stored) ----------------
template <int NSEG, int DOUT, int F32MASK>
__global__ __launch_bounds__(256) void fkan_kernel(
    const void* __restrict__ X0, int s0,
    const void* __restrict__ X1, int s1,
    const void* __restrict__ X2, int s2,
    const float2* __restrict__ ST0, const float2* __restrict__ ST1, const float2* __restrict__ ST2,
    const float* __restrict__ lng, const float* __restrict__ lnb,
    const ushortT* __restrict__ Wc,
    const float* __restrict__ bs, const float* __restrict__ bb,
    ushortT* __restrict__ H, int hstride, int nrows) {
    constexpr int DIN = NSEG * 128;
    constexpr int KW = 5 * DIN;
    constexpr int NT = (DOUT + 15) / 16;
    constexpr int NCH = NSEG * 2;
    constexpr bool RING = (F32MASK == 0) && (NSEG == 1);
    __shared__ float red[2][NT][4][64];
    int tid = threadIdx.x;
    int w = tid >> 6, lane = tid & 63;
    int m = lane & 15, q = lane >> 4;
    int r = w & 1;
    int kk = w >> 1;
    int baseA = blockIdx.x * 64 + r * 16;
    int baseB = baseA + 32;
    int rA = min(baseA + m, nrows - 1);
    int rB = min(baseB + m, nrows - 1);

    float muA, scA, muB, scB;
    {
        float2 st = ST0[rA]; float sum = st.x, ssq = st.y;
        if (NSEG == 3) { float2 t1 = ST1[rA]; sum += t1.x; ssq += t1.y; float2 t2 = ST2[rA]; sum += t2.x; ssq += t2.y; }
        muA = sum * (1.0f / DIN);
        float var = ssq * (1.0f / DIN) - muA * muA;
        scA = rsqrtf(fmaxf(var, 0.0f) + 1e-5f);
    }
    {
        float2 st = ST0[rB]; float sum = st.x, ssq = st.y;
        if (NSEG == 3) { float2 t1 = ST1[rB]; sum += t1.x; ssq += t1.y; float2 t2 = ST2[rB]; sum += t2.x; ssq += t2.y; }
        muB = sum * (1.0f / DIN);
        float var = ssq * (1.0f / DIN) - muB * muB;
        scB = rsqrtf(fmaxf(var, 0.0f) + 1e-5f);
    }

    float4v acc[NT][2];
    #pragma unroll
    for (int t = 0; t < NT; t++) {
        acc[t][0] = (float4v){0.f, 0.f, 0.f, 0.f};
        acc[t][1] = (float4v){0.f, 0.f, 0.f, 0.f};
    }

    const float CC = 0.90084159f;
    const __half2 Gc2[4] = {
        __float2half2_rn(-2.f * CC), __float2half2_rn(-2.f / 3.f * CC),
        __float2half2_rn(2.f / 3.f * CC), __float2half2_rn(2.f * CC)};
    const __half2 NL2E = __float2half2_rn(-1.44269504f);
    const __half2 ONE2 = __float2half2_rn(1.0f);

    uint4 rawA[2], rawB[2];
    if (RING) {
        int d00 = kk * 32 + q * 8;
        rawA[0] = *(const uint4*)((const ushortT*)X0 + (size_t)rA * s0 + d00);
        rawB[0] = *(const uint4*)((const ushortT*)X0 + (size_t)rB * s0 + d00);
    }

    #pragma unroll
    for (int h = 0; h < NCH; h++) {
        const int seg = h >> 1;
        int i = 2 * (h & 1) + kk;
        int d0 = i * 32 + q * 8;
        float xa[8], xb8[8];
        uint4 curA, curB;
        if (RING) {
            if (h + 1 < NCH) {
                int i2 = 2 * ((h + 1) & 1) + kk;
                int d2 = i2 * 32 + q * 8;
                rawA[(h + 1) & 1] = *(const uint4*)((const ushortT*)X0 + (size_t)rA * s0 + d2);
                rawB[(h + 1) & 1] = *(const uint4*)((const ushortT*)X0 + (size_t)rB * s0 + d2);
            }
            curA = rawA[h & 1];
            curB = rawB[h & 1];
            unpack8(curA, xa);
            unpack8(curB, xb8);
        } else {
            const void* Xp = (seg == 0) ? X0 : (seg == 1) ? X1 : X2;
            int str = (seg == 0) ? s0 : (seg == 1) ? s1 : s2;
            bool f32 = ((F32MASK >> seg) & 1) != 0;
            loadc8r(f32, Xp, (size_t)rA * str + d0, xa, curA);
            loadc8r(f32, Xp, (size_t)rB * str + d0, xb8, curB);
        }
        float4 gv0 = *(const float4*)(lng + seg * 128 + d0);
        float4 gv1 = *(const float4*)(lng + seg * 128 + d0 + 4);
        float4 bv0 = *(const float4*)(lnb + seg * 128 + d0);
        float4 bv1 = *(const float4*)(lnb + seg * 128 + d0 + 4);
        float gvs[8] = {gv0.x, gv0.y, gv0.z, gv0.w, gv1.x, gv1.y, gv1.z, gv1.w};
        float bvs[8] = {bv0.x, bv0.y, bv0.z, bv0.w, bv1.x, bv1.y, bv1.z, bv1.w};
        float za[8], zb[8];
        #pragma unroll
        for (int j = 0; j < 8; j++) {
            za[j] = (xa[j] - muA) * scA * gvs[j] + bvs[j];
            zb[j] = (xb8[j] - muB) * scB * gvs[j] + bvs[j];
        }
        __half2 zhA[4], zhB[4];
        #pragma unroll
        for (int p = 0; p < 4; p++) {
            zhA[p] = __builtin_bit_cast(__half2, pkrtz(za[2 * p] * CC, za[2 * p + 1] * CC));
            zhB[p] = __builtin_bit_cast(__half2, pkrtz(zb[2 * p] * CC, zb[2 * p + 1] * CC));
        }
        #pragma unroll
        for (int g = 0; g < 4; g++) {
            uint4v ua, ub;
            #pragma unroll
            for (int p = 0; p < 4; p++) {
                __half2 dA = __hsub2(zhA[p], Gc2[g]);
                ua[p] = __builtin_bit_cast(unsigned, h2exp2(__hmul2(dA, __hneg2(dA))));
                __half2 dB = __hsub2(zhB[p], Gc2[g]);
                ub[p] = __builtin_bit_cast(unsigned, h2exp2(__hmul2(dB, __hneg2(dB))));
            }
            f16x8 afa = __builtin_bit_cast(f16x8, ua);
            f16x8 afb = __builtin_bit_cast(f16x8, ub);
            int kbase = seg * 512 + g * 128 + i * 32;
            #pragma unroll
            for (int t = 0; t < NT; t++) {
                int n = t * 16 + m;
                f16x8 bfr = (f16x8)(_Float16)0;
                if ((DOUT % 16 == 0) || (n < DOUT))
                    bfr = *(const f16x8*)(Wc + (size_t)n * KW + kbase + q * 8);
                acc[t][0] = __builtin_amdgcn_mfma_f32_16x16x32_f16(afa, bfr, acc[t][0], 0, 0, 0);
                acc[t][1] = __builtin_amdgcn_mfma_f32_16x16x32_f16(afb, bfr, acc[t][1], 0, 0, 0);
            }
        }
        {
            unsigned raA[4] = {curA.x, curA.y, curA.z, curA.w};
            unsigned raB[4] = {curB.x, curB.y, curB.z, curB.w};
            uint4v ua, ub;
            #pragma unroll
            for (int p = 0; p < 4; p++) {
                __half2 xhA = __builtin_bit_cast(__half2, raA[p]);
                __half2 sgA = h2rcp(__hadd2(ONE2, h2exp2(__hmul2(xhA, NL2E))));
                ua[p] = __builtin_bit_cast(unsigned, __hmul2(xhA, sgA));
                __half2 xhB = __builtin_bit_cast(__half2, raB[p]);
                __half2 sgB = h2rcp(__hadd2(ONE2, h2exp2(__hmul2(xhB, NL2E))));
                ub[p] = __builtin_bit_cast(unsigned, __hmul2(xhB, sgB));
            }
            f16x8 afa = __builtin_bit_cast(f16x8, ua);
            f16x8 afb = __builtin_bit_cast(f16x8, ub);
            int kbase = 4 * DIN + seg * 128 + i * 32;
            #pragma unroll
            for (int t = 0; t < NT; t++) {
                int n = t * 16 + m;
                f16x8 bfr = (f16x8)(_Float16)0;
                if ((DOUT % 16 == 0) || (n < DOUT))
                    bfr = *(const f16x8*)(Wc + (size_t)n * KW + kbase + q * 8);
                acc[t][0] = __builtin_amdgcn_mfma_f32_16x16x32_f16(afa, bfr, acc[t][0], 0, 0, 0);
                acc[t][1] = __builtin_amdgcn_mfma_f32_16x16x32_f16(afb, bfr, acc[t][1], 0, 0, 0);
            }
        }
    }

    if (kk == 1) {
        #pragma unroll
        for (int t = 0; t < NT; t++)
            #pragma unroll
            for (int j = 0; j < 4; j++) red[r][t][j][lane] = acc[t][0][j];
    }
    __syncthreads();
    if (kk == 0) {
        #pragma unroll
        for (int t = 0; t < NT; t++)
            #pragma unroll
            for (int j = 0; j < 4; j++) {
                acc[t][0][j] += red[r][t][j][lane];
                red[r][t][j][lane] = acc[t][1][j];
            }
    }
    __syncthreads();
    if (kk == 1) {
        #pragma unroll
        for (int t = 0; t < NT; t++)
            #pragma unroll
            for (int j = 0; j < 4; j++) acc[t][1][j] += red[r][t][j][lane];
    }

    int gbase = (kk == 0) ? baseA : baseB;
    int side = (kk == 0) ? 0 : 1;
    #pragma unroll
    for (int t = 0; t < NT; t++) {
        int col = t * 16 + m;
        if ((DOUT % 16 == 0) || (col < DOUT)) {
            float bias = bs[col] + bb[col];
            #pragma unroll
            for (int j = 0; j < 4; j++) {
                int row = gbase + q * 4 + j;
                if (row < nrows) H[(size_t)row * hstride + col] = f2h(acc[t][side][j] + bias);
            }
        }
    }
}

// ---------------- aggregation: wave per node (r9 shape); dinv applied in-gather ----------------
// H (f16) is RAW h. out = dinv[wid]*(dinv[wid]*h[wid] + sum dinv[s]*h[s]) + bg.

__global__ __launch_bounds__(256) void agg128_kernel(
    const ushortT* __restrict__ H, ushortT* __restrict__ OUT,
    const float* __restrict__ bg, const int* __restrict__ rowptr,
    const int* __restrict__ colv, const float* __restrict__ dinv,
    float2* __restrict__ STout, int n) {
    int wid = (blockIdx.x * 256 + threadIdx.x) >> 6;
    int lane = threadIdx.x & 63;
    if (wid >= n) return;
    int g = lane >> 4, t = lane & 15;
    float di = dinv[wid];
    float a[8] = {0.f, 0.f, 0.f, 0.f, 0.f, 0.f, 0.f, 0.f};
    if (g == 0) unpack_fma(*(const uint4*)(H + (size_t)wid * 128 + t * 8), di, a);  // self
    int e0 = rowptr[wid], e1 = rowptr[wid + 1];
    int e = e0 + g;
    for (; e + 4 < e1; e += 8) {
        int s0i = colv[e], s1i = colv[e + 4];
        float d0v = dinv[s0i], d1v = dinv[s1i];
        uint4 v0 = *(const uint4*)(H + (size_t)s0i * 128 + t * 8);
        uint4 v1 = *(const uint4*)(H + (size_t)s1i * 128 + t * 8);
        unpack_fma(v0, d0v, a);
        unpack_fma(v1, d1v, a);
    }
    if (e < e1) {
        int si = colv[e];
        unpack_fma(*(const uint4*)(H + (size_t)si * 128 + t * 8), dinv[si], a);
    }
    #pragma unroll
    for (int j = 0; j < 8; j++) {
        a[j] += __shfl_xor(a[j], 16);
        a[j] += __shfl_xor(a[j], 32);
    }
    if (g == 0) {
        float4 b0 = *(const float4*)(bg + t * 8);
        float4 b1 = *(const float4*)(bg + t * 8 + 4);
        float bgs[8] = {b0.x, b0.y, b0.z, b0.w, b1.x, b1.y, b1.z, b1.w};
        unsigned rb[8];
        float s = 0.f, ss = 0.f;
        #pragma unroll
        for (int j = 0; j < 8; j++) {
            float o = di * a[j] + bgs[j];
            rb[j] = f2h(o);                       // RTNE; stored value
            float back = h2f((unsigned short)rb[j]);
            s += back; ss += back * back;         // stats of STORED values (LN consistency)
        }
        uint4 pk;
        pk.x = rb[0] | (rb[1] << 16);
        pk.y = rb[2] | (rb[3] << 16);
        pk.z = rb[4] | (rb[5] << 16);
        pk.w = rb[6] | (rb[7] << 16);
        *(uint4*)(OUT + (size_t)wid * 128 + t * 8) = pk;
        #pragma unroll
        for (int d = 1; d < 16; d <<= 1) { s += __shfl_xor(s, d); ss += __shfl_xor(ss, d); }
        if (t == 0) STout[wid] = make_float2(s, ss);
    }
}

// H stride 64 (cols 47..63 junk, never written out). dinv in-gather.
__global__ __launch_bounds__(256) void agg47_kernel(
    const ushortT* __restrict__ H, float* __restrict__ OUT,
    const float* __restrict__ bg, const int* __restrict__ rowptr,
    const int* __restrict__ colv, const float* __restrict__ dinv, int n) {
    int wid = (blockIdx.x * 256 + threadIdx.x) >> 6;
    int lane = threadIdx.x & 63;
    if (wid >= n) return;
    int g = lane >> 3, t = lane & 7;
    float di = dinv[wid];
    float a[8] = {0.f, 0.f, 0.f, 0.f, 0.f, 0.f, 0.f, 0.f};
    if (g == 0) unpack_fma(*(const uint4*)(H + (size_t)wid * 64 + t * 8), di, a);  // self
    int e0 = rowptr[wid], e1 = rowptr[wid + 1];
    int e = e0 + g;
    for (; e + 8 < e1; e += 16) {
        int s0i = colv[e], s1i = colv[e + 8];
        float d0v = dinv[s0i], d1v = dinv[s1i];
        uint4 v0 = *(const uint4*)(H + (size_t)s0i * 64 + t * 8);
        uint4 v1 = *(const uint4*)(H + (size_t)s1i * 64 + t * 8);
        unpack_fma(v0, d0v, a);
        unpack_fma(v1, d1v, a);
    }
    if (e < e1) {
        int si = colv[e];
        unpack_fma(*(const uint4*)(H + (size_t)si * 64 + t * 8), dinv[si], a);
    }
    #pragma unroll
    for (int j = 0; j < 8; j++) {
        a[j] += __shfl_xor(a[j], 8);
        a[j] += __shfl_xor(a[j], 16);
        a[j] += __shfl_xor(a[j], 32);
    }
    if (g == 0) {
        #pragma unroll
        for (int j = 0; j < 8; j++) {
            int c = t * 8 + j;
            if (c < 47) OUT[(size_t)wid * 47 + c] = di * a[j] + bg[c];
        }
    }
}

// ---------------- launcher ----------------

extern "C" void kernel_launch(void* const* d_in, const int* in_sizes, int n_in,
                              void* d_out, int out_size, void* d_ws, size_t ws_size,
                              hipStream_t stream) {
    const float* x = (const float*)d_in[0];
    const int* ei = (const int*)d_in[1];
    const float* lng0 = (const float*)d_in[2];
    const float* lnb0 = (const float*)d_in[3];
    const float* Ws0 = (const float*)d_in[4];
    const float* bs0 = (const float*)d_in[5];
    const float* Wb0 = (const float*)d_in[6];
    const float* bb0 = (const float*)d_in[7];
    const float* bg0 = (const float*)d_in[8];
    const float* lng1 = (const float*)d_in[9];
    const float* lnb1 = (const float*)d_in[10];
    const float* Ws1 = (const float*)d_in[11];
    const float* bs1 = (const float*)d_in[12];
    const float* Wb1 = (const float*)d_in[13];
    const float* bb1 = (const float*)d_in[14];
    const float* bg1 = (const float*)d_in[15];
    const float* lng2 = (const float*)d_in[16];
    const float* lnb2 = (const float*)d_in[17];
    const float* Ws2 = (const float*)d_in[18];
    const float* bs2 = (const float*)d_in[19];
    const float* Wb2 = (const float*)d_in[20];
    const float* bb2 = (const float*)d_in[21];
    const float* bg2 = (const float*)d_in[22];

    const int N = in_sizes[0] / 128;
    const int E = in_sizes[1] / 2;
    const int NB = (N + 255) >> 8;  // coarse buckets of 256 nodes (requires N < 2^24)

    char* wsp = (char*)d_ws;
    size_t off = 0;
    auto alloc = [&](size_t bytes) {
        off = (off + 255) & ~(size_t)255;
        void* p = wsp + off;
        off += bytes;
        return p;
    };
    int* ghist = (int*)alloc(512 * 4);
    int* bbase = (int*)alloc(513 * 4);
    int* gcur = (int*)alloc(512 * 4);
    int* rowptr = (int*)alloc((size_t)(N + 1) * 4);
    int* colv = (int*)alloc((size_t)E * 4);
    float* dinvv = (float*)alloc((size_t)N * 4);
    ushortT* hbuf = (ushortT*)alloc((size_t)N * 128 * 2);   // H1/H2/H3
    ushortT* a1 = (ushortT*)alloc((size_t)N * 128 * 2);
    ushortT* a2 = (ushortT*)alloc((size_t)N * 128 * 2);
    float2* stx = (float2*)alloc((size_t)N * 8);
    float2* st1 = (float2*)alloc((size_t)N * 8);
    float2* st2 = (float2*)alloc((size_t)N * 8);
    ushortT* Wc0 = (ushortT*)alloc((size_t)128 * 640 * 2);
    ushortT* Wc1 = (ushortT*)alloc((size_t)128 * 640 * 2);
    ushortT* Wc2 = (ushortT*)alloc((size_t)47 * 1920 * 2);
    size_t off_base = off;
    ushortT* xb = (ushortT*)alloc((size_t)N * 128 * 2);  // f16 mirror of x
    bool fits = (off <= ws_size);
    if (!fits) off = off_base;
    (void)n_in; (void)out_size;

    // pairs aliases a2 (NOT hbuf): a2 first written at agg128-2, pairs dead after the
    // fused csr_fkan1 launch — so fine_csr can read pairs while fkan1 writes hbuf.
    unsigned* pairs = (unsigned*)a2;

    const int* srcp = ei;
    const int* dstp = ei + E;

    int gF = (N + 63) / 64;
    int gW = (N + 3) / 4;
    int gScat = (E + SCAT_CH - 1) / SCAT_CH;

    // L1: Wc builds + ghist zero + LN stats (all input-only) in ONE launch
    build_wc3s<<<995 + gW, 256, 0, stream>>>(Ws0, Wb0, Wc0, Ws1, Wb1, Wc1, Ws2, Wb2, Wc2,
                                             ghist, x, stx, fits ? xb : nullptr, N);

    // L2-L4: coarse CSR
    coarse_hist<<<NB, 256, 0, stream>>>(dstp, ghist, E, NB);
    bucket_scan<<<1, 64, 0, stream>>>(ghist, bbase, gcur, NB);
    coarse_scatter<<<gScat, 256, 0, stream>>>(srcp, dstp, gcur, pairs, E, NB);

    // L5: fine CSR overlapped with layer-1 fkan (grid-partitioned)
    if (fits)
        csr_fkan1<0><<<NB + gF, 256, 0, stream>>>(pairs, bbase, rowptr, colv, dinvv, NB, E,
                                                  xb, 128, stx, lng0, lnb0, Wc0, bs0, bb0, hbuf, N);
    else
        csr_fkan1<1><<<NB + gF, 256, 0, stream>>>(pairs, bbase, rowptr, colv, dinvv, NB, E,
                                                  x, 128, stx, lng0, lnb0, Wc0, bs0, bb0, hbuf, N);

    // L6: aggregate H1 -> a1 (+st1)
    agg128_kernel<<<gW, 256, 0, stream>>>(hbuf, a1, bg0, rowptr, colv, dinvv, st1, N);

    // L7: layer 2 transform a1 -> H2 (hbuf)
    fkan_kernel<1, 128, 0><<<gF, 256, 0, stream>>>(a1, 128, a1, 128, a1, 128, st1, st1, st1,
                                                   lng1, lnb1, Wc1, bs1, bb1, hbuf, 128, N);
    // L8: aggregate H2 -> a2 (+st2)   [overwrites the dead pairs alias]
    agg128_kernel<<<gW, 256, 0, stream>>>(hbuf, a2, bg1, rowptr, colv, dinvv, st2, N);

    // L9: layer 3 transform (x|a1|a2) -> H3 (hbuf stride 64)
    if (fits)
        fkan_kernel<3, 47, 0><<<gF, 256, 0, stream>>>(xb, 128, a1, 128, a2, 128, stx, st1, st2,
                                                      lng2, lnb2, Wc2, bs2, bb2, hbuf, 64, N);
    else
        fkan_kernel<3, 47, 1><<<gF, 256, 0, stream>>>(x, 128, a1, 128, a2, 128, stx, st1, st2,
                                                      lng2, lnb2, Wc2, bs2, bb2, hbuf, 64, N);
    // L10: final aggregate -> out
    agg47_kernel<<<gW, 256, 0, stream>>>(hbuf, (float*)d_out, bg2, rowptr, colv, dinvv, N);
}